// Round 2
// baseline (604.039 us; speedup 1.0000x reference)
//
#include <hip/hip_runtime.h>

#define D1 96
#define GRID_VOX (D1 * D1 * D1)
#define NCAP 4096  // per-group pair-list capacity (expected ~450/group, 9x margin)

// ---------------------------------------------------------------------------
// Scatter active voxel indices into dense level-1 lookup grid (pre-memset -1)
// ---------------------------------------------------------------------------
__global__ void scatter_grid_kernel(const int* __restrict__ coords,
                                    int* __restrict__ grid, int n) {
    int i = blockIdx.x * blockDim.x + threadIdx.x;
    if (i < n) {
        int c0 = coords[3 * i], c1 = coords[3 * i + 1], c2 = coords[3 * i + 2];
        grid[(c0 * D1 + c1) * D1 + c2] = i;
    }
}

// ---------------------------------------------------------------------------
// W1T[k][co][ci] = W1[k][ci][co]   (transposed so a wave can read one co-row
// of 64 floats contiguously / wave-uniformly)
// ---------------------------------------------------------------------------
__global__ void transpose_w1_kernel(const float* __restrict__ W1,
                                    float* __restrict__ W1T) {
    int t = blockIdx.x * blockDim.x + threadIdx.x;
    if (t >= 27 * 4096) return;
    int k = t >> 12, r = t & 4095;
    int co = r >> 6, ci = r & 63;
    W1T[t] = W1[k * 4096 + ci * 64 + co];
}

// ---------------------------------------------------------------------------
// Folded + transposed conv2 weights:
// W2T[s*8+d][co][ci] = sum_{o -> (s,d)} W2[o][ci][co]
// Per axis: p = s-1+d; o in [max(-1,2p-s), min(1,2p+1-s)]
// ---------------------------------------------------------------------------
__global__ void build_w2eff_t_kernel(const float* __restrict__ W2,
                                     float* __restrict__ W2T) {
    int sd = blockIdx.x;
    int s = sd >> 3, d = sd & 7;
    int sa[3] = { (s >> 2) & 1, (s >> 1) & 1, s & 1 };
    int da[3] = { (d >> 2) & 1, (d >> 1) & 1, d & 1 };
    int lo[3], hi[3];
#pragma unroll
    for (int a = 0; a < 3; ++a) {
        int p = sa[a] - 1 + da[a];
        int l = 2 * p - sa[a];
        int h = 2 * p + 1 - sa[a];
        lo[a] = l < -1 ? -1 : l;
        hi[a] = h > 1 ? 1 : h;
    }
    for (int e = threadIdx.x; e < 4096; e += blockDim.x) {
        int co = e >> 6, ci = e & 63;
        float sum = 0.0f;
        for (int o0 = lo[0]; o0 <= hi[0]; ++o0)
            for (int o1 = lo[1]; o1 <= hi[1]; ++o1)
                for (int o2 = lo[2]; o2 <= hi[2]; ++o2) {
                    int k = (o0 + 1) * 9 + (o1 + 1) * 3 + (o2 + 1);
                    sum += W2[k * 4096 + ci * 64 + co];
                }
        W2T[sd * 4096 + e] = sum;
    }
}

// ---------------------------------------------------------------------------
// Build compacted pair lists. Thread per (voxel, tap).
// conv1: group k (center k=13 excluded, handled dense)  -> (row=i, src=j)
// conv2: groups gid=s*8+d for off=s-1+d (center excluded)-> (row=i*8+s, src=j)
// ---------------------------------------------------------------------------
__global__ void build_pairs_kernel(const int* __restrict__ coords,
                                   const int* __restrict__ grid,
                                   int2* __restrict__ pairs1, int* __restrict__ c1,
                                   int2* __restrict__ pairs2, int* __restrict__ c2,
                                   int n) {
    int t = blockIdx.x * blockDim.x + threadIdx.x;
    if (t >= n * 27) return;
    int i = t / 27, k = t % 27;
    if (k == 13) return;  // self tap: handled by dense kernels
    int o[3] = { k / 9 - 1, (k / 3) % 3 - 1, k % 3 - 1 };
    int x0 = coords[3 * i] + o[0];
    int x1 = coords[3 * i + 1] + o[1];
    int x2 = coords[3 * i + 2] + o[2];
    if ((unsigned)x0 >= D1 || (unsigned)x1 >= D1 || (unsigned)x2 >= D1) return;
    int j = grid[(x0 * D1 + x1) * D1 + x2];
    if (j < 0) return;

    // conv1 pair
    int slot = atomicAdd(&c1[k], 1);
    if (slot < NCAP) pairs1[k * NCAP + slot] = make_int2(i, j);

    // conv2 (s,d) combos for this offset: per axis o=-1 ->(0,0); 0 ->(0,1),(1,0); 1 ->(1,1)
    int cnt[3], sopt[3][2], dopt[3][2];
#pragma unroll
    for (int a = 0; a < 3; ++a) {
        if (o[a] == -1)     { cnt[a] = 1; sopt[a][0] = 0; dopt[a][0] = 0; }
        else if (o[a] == 0) { cnt[a] = 2; sopt[a][0] = 0; dopt[a][0] = 1;
                                          sopt[a][1] = 1; dopt[a][1] = 0; }
        else                { cnt[a] = 1; sopt[a][0] = 1; dopt[a][0] = 1; }
    }
    for (int a0 = 0; a0 < cnt[0]; ++a0)
        for (int a1 = 0; a1 < cnt[1]; ++a1)
            for (int a2 = 0; a2 < cnt[2]; ++a2) {
                int s = (sopt[0][a0] << 2) | (sopt[1][a1] << 1) | sopt[2][a2];
                int d = (dopt[0][a0] << 2) | (dopt[1][a1] << 1) | dopt[2][a2];
                int gid = s * 8 + d;
                int slot2 = atomicAdd(&c2[gid], 1);
                if (slot2 < NCAP) pairs2[gid * NCAP + slot2] = make_int2(i * 8 + s, j);
            }
}

// ---------------------------------------------------------------------------
// Register-tiled 64x64 matvec block: lane = row, features in 16 float4 VGPRs,
// weights wave-uniform (scalar/broadcast loads).
// ---------------------------------------------------------------------------
__device__ __forceinline__ void fma_rows(float4& acc, const float4 f[16],
                                         const float4* __restrict__ w4, int cg) {
#pragma unroll
    for (int q = 0; q < 16; ++q) {
        float4 fq = f[q];
        float4 wa = w4[(cg * 4 + 0) * 16 + q];
        float4 wb = w4[(cg * 4 + 1) * 16 + q];
        float4 wc = w4[(cg * 4 + 2) * 16 + q];
        float4 wd = w4[(cg * 4 + 3) * 16 + q];
        acc.x += fq.x * wa.x + fq.y * wa.y + fq.z * wa.z + fq.w * wa.w;
        acc.y += fq.x * wb.x + fq.y * wb.y + fq.z * wb.z + fq.w * wb.w;
        acc.z += fq.x * wc.x + fq.y * wc.y + fq.z * wc.z + fq.w * wc.w;
        acc.w += fq.x * wd.x + fq.y * wd.y + fq.z * wd.z + fq.w * wd.w;
    }
}

// ---------------------------------------------------------------------------
// conv1 dense (self tap k=13): h[i] = b1 + feats[i] @ W1[13]
// 256 threads = 4 independent waves; LDS transpose for coalesced stores.
// ---------------------------------------------------------------------------
__global__ __launch_bounds__(256) void conv1_dense_kernel(
    const float* __restrict__ feats, const float* __restrict__ W1T,
    const float* __restrict__ b1, float* __restrict__ h, int n) {
    __shared__ float lds[4][64 * 65];
    int wave = threadIdx.x >> 6, lane = threadIdx.x & 63;
    int i = blockIdx.x * 256 + wave * 64 + lane;
    int rowbase = blockIdx.x * 256 + wave * 64;
    const float4* w4 = (const float4*)(W1T + 13 * 4096);
    const float4* b4 = (const float4*)b1;
    if (i < n) {
        const float4* f4 = (const float4*)(feats + (size_t)i * 64);
        float4 f[16];
#pragma unroll
        for (int q = 0; q < 16; ++q) f[q] = f4[q];
#pragma unroll
        for (int cg = 0; cg < 16; ++cg) {
            float4 acc = b4[cg];
            fma_rows(acc, f, w4, cg);
            *(float4*)&lds[wave][lane * 65 + cg * 4] = acc;
        }
    }
    __syncthreads();
    // coalesced store: 16 iters of float4 per lane over the 64x64 tile
    int nrows = n - rowbase;
    if (nrows > 64) nrows = 64;
    if (nrows > 0) {
#pragma unroll
        for (int j = 0; j < 16; ++j) {
            int flat = j * 256 + lane * 4;  // dword index in 64x64 tile
            int r = flat >> 6, c = flat & 63;
            if (r < nrows)
                *(float4*)&h[(size_t)(rowbase + r) * 64 + c] =
                    *(float4*)&lds[wave][r * 65 + c];
        }
    }
}

// ---------------------------------------------------------------------------
// conv2 dense (center slot): out[i*8+s] = b2 + h[i] @ W2T[s*8 + (s^7)]
// grid = (chunks, 8 s-groups)
// ---------------------------------------------------------------------------
__global__ __launch_bounds__(256) void conv2_dense_kernel(
    const float* __restrict__ h, const float* __restrict__ W2T,
    const float* __restrict__ b2, float* __restrict__ out, int n) {
    __shared__ float lds[4][64 * 65];
    int wave = threadIdx.x >> 6, lane = threadIdx.x & 63;
    int s = blockIdx.y;
    int i = blockIdx.x * 256 + wave * 64 + lane;
    int ibase = blockIdx.x * 256 + wave * 64;
    const float4* w4 = (const float4*)(W2T + (size_t)(s * 8 + (s ^ 7)) * 4096);
    const float4* b4 = (const float4*)b2;
    if (i < n) {
        const float4* f4 = (const float4*)(h + (size_t)i * 64);
        float4 f[16];
#pragma unroll
        for (int q = 0; q < 16; ++q) f[q] = f4[q];
#pragma unroll
        for (int cg = 0; cg < 16; ++cg) {
            float4 acc = b4[cg];
            fma_rows(acc, f, w4, cg);
            *(float4*)&lds[wave][lane * 65 + cg * 4] = acc;
        }
    }
    __syncthreads();
    // store rows (i*8+s) for i in [ibase, ibase+64): scattered rows but each
    // row's 256B written via 4 coalesced-ish float4 bursts from LDS
    int nrows = n - ibase;
    if (nrows > 64) nrows = 64;
    if (nrows > 0) {
#pragma unroll
        for (int j = 0; j < 16; ++j) {
            int flat = j * 256 + lane * 4;
            int r = flat >> 6, c = flat & 63;
            if (r < nrows)
                *(float4*)&out[((size_t)(ibase + r) * 8 + s) * 64 + c] =
                    *(float4*)&lds[wave][r * 65 + c];
        }
    }
}

// ---------------------------------------------------------------------------
// Sparse groups: out[row] += src[j] @ WT[gid]  via atomics.
// grid = (NCAP/256, ngroups); 256 threads = 4 waves, each wave one 64-chunk.
// ---------------------------------------------------------------------------
__global__ __launch_bounds__(256) void sparse_kernel(
    const int2* __restrict__ pairs, const int* __restrict__ counters,
    const float* __restrict__ WT, const float* __restrict__ src,
    float* __restrict__ out) {
    int gid = blockIdx.y;
    int count = counters[gid];
    if (count > NCAP) count = NCAP;
    int wave = threadIdx.x >> 6, lane = threadIdx.x & 63;
    int p = blockIdx.x * 256 + wave * 64 + lane;
    if (blockIdx.x * 256 + wave * 64 >= count) return;  // wave-uniform exit
    bool valid = p < count;
    int2 pr = pairs[gid * NCAP + (valid ? p : 0)];
    const float4* w4 = (const float4*)(WT + (size_t)gid * 4096);
    const float4* f4 = (const float4*)(src + (size_t)pr.y * 64);
    float4 f[16];
#pragma unroll
    for (int q = 0; q < 16; ++q) f[q] = f4[q];
    float* orow = out + (size_t)pr.x * 64;
#pragma unroll
    for (int cg = 0; cg < 16; ++cg) {
        float4 acc = make_float4(0.f, 0.f, 0.f, 0.f);
        fma_rows(acc, f, w4, cg);
        if (valid) {
            atomicAdd(&orow[cg * 4 + 0], acc.x);
            atomicAdd(&orow[cg * 4 + 1], acc.y);
            atomicAdd(&orow[cg * 4 + 2], acc.z);
            atomicAdd(&orow[cg * 4 + 3], acc.w);
        }
    }
}

// ---------------------------------------------------------------------------
// In-place SiLU, vectorized float4, grid-stride
// ---------------------------------------------------------------------------
__global__ void silu_kernel(float* __restrict__ x, int n4) {
    int t = blockIdx.x * blockDim.x + threadIdx.x;
    for (; t < n4; t += gridDim.x * blockDim.x) {
        float4 v = ((float4*)x)[t];
        v.x = v.x / (1.0f + __expf(-v.x));
        v.y = v.y / (1.0f + __expf(-v.y));
        v.z = v.z / (1.0f + __expf(-v.z));
        v.w = v.w / (1.0f + __expf(-v.w));
        ((float4*)x)[t] = v;
    }
}

// ---------------------------------------------------------------------------
extern "C" void kernel_launch(void* const* d_in, const int* in_sizes, int n_in,
                              void* d_out, int out_size, void* d_ws,
                              size_t ws_size, hipStream_t stream) {
    const int* coords = (const int*)d_in[0];
    const float* feats = (const float*)d_in[1];
    const float* W1 = (const float*)d_in[2];
    const float* b1 = (const float*)d_in[3];
    const float* W2 = (const float*)d_in[4];
    const float* b2 = (const float*)d_in[5];
    float* out = (float*)d_out;

    int n = in_sizes[0] / 3;  // 20000

    // workspace layout (256B-aligned sections)
    char* ws = (char*)d_ws;
    size_t off = 0;
    auto alloc = [&](size_t bytes) {
        size_t o = off;
        off = (off + bytes + 255) & ~(size_t)255;
        return o;
    };
    int*   grid1  = (int*)(ws + alloc((size_t)GRID_VOX * 4));   // 3.54 MB
    float* h      = (float*)(ws + alloc((size_t)n * 64 * 4));   // 5.12 MB
    float* W1T    = (float*)(ws + alloc(27 * 4096 * 4));        // 0.44 MB
    float* W2T    = (float*)(ws + alloc(64 * 4096 * 4));        // 1.0 MB
    int*   cnts   = (int*)(ws + alloc(128 * 4));                // c1[27] + c2[64]
    int2*  pairs1 = (int2*)(ws + alloc((size_t)27 * NCAP * 8)); // 0.88 MB
    int2*  pairs2 = (int2*)(ws + alloc((size_t)64 * NCAP * 8)); // 2.1 MB
    int* c1 = cnts;
    int* c2 = cnts + 32;

    // 1. clear grid (-1) and counters (0)
    hipMemsetAsync(grid1, 0xFF, (size_t)GRID_VOX * 4, stream);
    hipMemsetAsync(cnts, 0, 128 * 4, stream);

    // 2. scatter grid, prep weights, build pair lists
    scatter_grid_kernel<<<(n + 255) / 256, 256, 0, stream>>>(coords, grid1, n);
    transpose_w1_kernel<<<(27 * 4096 + 255) / 256, 256, 0, stream>>>(W1, W1T);
    build_w2eff_t_kernel<<<64, 256, 0, stream>>>(W2, W2T);
    build_pairs_kernel<<<(n * 27 + 255) / 256, 256, 0, stream>>>(
        coords, grid1, pairs1, c1, pairs2, c2, n);

    // 3. conv1: dense self-tap write, sparse atomics, SiLU in place
    conv1_dense_kernel<<<(n + 255) / 256, 256, 0, stream>>>(feats, W1T, b1, h, n);
    sparse_kernel<<<dim3(NCAP / 256, 27), 256, 0, stream>>>(pairs1, c1, W1T, feats, h);
    silu_kernel<<<1024, 256, 0, stream>>>(h, n * 64 / 4);

    // 4. conv2: dense center-slot write, sparse atomics, SiLU in place
    conv2_dense_kernel<<<dim3((n + 255) / 256, 8), 256, 0, stream>>>(h, W2T, b2, out, n);
    sparse_kernel<<<dim3(NCAP / 256, 64), 256, 0, stream>>>(pairs2, c2, W2T, h, out);
    silu_kernel<<<2048, 256, 0, stream>>>(out, n * 8 * 64 / 4);
}

// Round 3
// 246.861 us; speedup vs baseline: 2.4469x; 2.4469x over previous
//
#include <hip/hip_runtime.h>

#define D1 96
#define GRID_VOX (D1 * D1 * D1)
#define CAP1 32   // max 26 non-center taps per parent (exact bound)
#define CAP2 64   // max 56 (s,d) combos per parent (exact bound)

// ---------------------------------------------------------------------------
__global__ void scatter_grid_kernel(const int* __restrict__ coords,
                                    int* __restrict__ grid, int n) {
    int i = blockIdx.x * blockDim.x + threadIdx.x;
    if (i < n)
        grid[(coords[3 * i] * D1 + coords[3 * i + 1]) * D1 + coords[3 * i + 2]] = i;
}

// ---------------------------------------------------------------------------
// W1T13[co*64+ci] = W1[13][ci][co]                      (4096 elems)
// W2Tc[s][co*64+ci] = sum_{8 center taps} W2[k][ci][co] (8*4096)
// W2e[sd][ci*64+co] = sum_{taps->sd} W2[k][ci][co]      (64*4096, NO transpose)
// ---------------------------------------------------------------------------
__global__ void prep_weights_kernel(const float* __restrict__ W1,
                                    const float* __restrict__ W2,
                                    float* __restrict__ W1T13,
                                    float* __restrict__ W2Tc,
                                    float* __restrict__ W2e) {
    int t = blockIdx.x * blockDim.x + threadIdx.x;
    if (t >= 73 * 4096) return;
    if (t < 4096) {
        int co = t >> 6, ci = t & 63;
        W1T13[t] = W1[13 * 4096 + ci * 64 + co];
    } else if (t < 9 * 4096) {
        int r = t - 4096;
        int s = r >> 12, e = r & 4095;
        int co = e >> 6, ci = e & 63;
        int sa[3] = { (s >> 2) & 1, (s >> 1) & 1, s & 1 };
        float sum = 0.f;
        for (int o0 = -sa[0]; o0 <= 1 - sa[0]; ++o0)
            for (int o1 = -sa[1]; o1 <= 1 - sa[1]; ++o1)
                for (int o2 = -sa[2]; o2 <= 1 - sa[2]; ++o2) {
                    int k = (o0 + 1) * 9 + (o1 + 1) * 3 + (o2 + 1);
                    sum += W2[k * 4096 + ci * 64 + co];
                }
        W2Tc[s * 4096 + co * 64 + ci] = sum;
    } else {
        int r = t - 9 * 4096;
        int sd = r >> 12, e = r & 4095;  // e = ci*64+co (same layout as W2)
        int s = sd >> 3, d = sd & 7;
        int sa[3] = { (s >> 2) & 1, (s >> 1) & 1, s & 1 };
        int da[3] = { (d >> 2) & 1, (d >> 1) & 1, d & 1 };
        int lo[3], hi[3];
        for (int a = 0; a < 3; ++a) {
            int p = sa[a] - 1 + da[a];
            int l = 2 * p - sa[a];     if (l < -1) l = -1;
            int h = 2 * p + 1 - sa[a]; if (h > 1) h = 1;
            lo[a] = l; hi[a] = h;
        }
        float sum = 0.f;
        for (int o0 = lo[0]; o0 <= hi[0]; ++o0)
            for (int o1 = lo[1]; o1 <= hi[1]; ++o1)
                for (int o2 = lo[2]; o2 <= hi[2]; ++o2) {
                    int k = (o0 + 1) * 9 + (o1 + 1) * 3 + (o2 + 1);
                    sum += W2[k * 4096 + e];
                }
        W2e[sd * 4096 + e] = sum;
    }
}

// ---------------------------------------------------------------------------
// Per-parent pair lists. Entry = j | (tag << 20); tag = k (conv1) or sd (conv2)
// ---------------------------------------------------------------------------
__global__ void build_pairs_kernel(const int* __restrict__ coords,
                                   const int* __restrict__ grid,
                                   int* __restrict__ c1, int* __restrict__ p1,
                                   int* __restrict__ c2, int* __restrict__ p2,
                                   int n) {
    int t = blockIdx.x * blockDim.x + threadIdx.x;
    if (t >= n * 27) return;
    int i = t / 27, k = t % 27;
    if (k == 13) return;  // center handled dense
    int o[3] = { k / 9 - 1, (k / 3) % 3 - 1, k % 3 - 1 };
    int x0 = coords[3 * i] + o[0];
    int x1 = coords[3 * i + 1] + o[1];
    int x2 = coords[3 * i + 2] + o[2];
    if ((unsigned)x0 >= D1 || (unsigned)x1 >= D1 || (unsigned)x2 >= D1) return;
    int j = grid[(x0 * D1 + x1) * D1 + x2];
    if (j < 0) return;

    int s1 = atomicAdd(&c1[i], 1);
    p1[i * CAP1 + s1] = j | (k << 20);

    // conv2 (s,d) combos: per axis o=-1 ->(0,0); 0 ->(0,1),(1,0); 1 ->(1,1)
    int cnt[3], sopt[3][2], dopt[3][2];
#pragma unroll
    for (int a = 0; a < 3; ++a) {
        if (o[a] == -1)     { cnt[a] = 1; sopt[a][0] = 0; dopt[a][0] = 0; }
        else if (o[a] == 0) { cnt[a] = 2; sopt[a][0] = 0; dopt[a][0] = 1;
                                          sopt[a][1] = 1; dopt[a][1] = 0; }
        else                { cnt[a] = 1; sopt[a][0] = 1; dopt[a][0] = 1; }
    }
    for (int a0 = 0; a0 < cnt[0]; ++a0)
        for (int a1 = 0; a1 < cnt[1]; ++a1)
            for (int a2 = 0; a2 < cnt[2]; ++a2) {
                int s = (sopt[0][a0] << 2) | (sopt[1][a1] << 1) | sopt[2][a2];
                int d = (dopt[0][a0] << 2) | (dopt[1][a1] << 1) | dopt[2][a2];
                int s2 = atomicAdd(&c2[i], 1);
                p2[i * CAP2 + s2] = j | ((s * 8 + d) << 20);
            }
}

// ---------------------------------------------------------------------------
// conv1 fused: dense self-tap (lane=row, SGPR weights) + per-pair fixup
// (lane=co, uniform f_j, vector W1 loads) + SiLU epilogue. 1 wave / 64 rows.
// ---------------------------------------------------------------------------
__global__ __launch_bounds__(64, 2) void conv1_fused_kernel(
    const float* __restrict__ feats, const float* __restrict__ W1,
    const float* __restrict__ W1T13, const float* __restrict__ b1,
    const int* __restrict__ c1, const int* __restrict__ p1,
    float* __restrict__ h, int n) {
    int base = blockIdx.x * 64, lane = threadIdx.x;
    int i = base + lane;
    bool valid = i < n;
    const float4* w4 = (const float4*)W1T13;
    const float4* b4 = (const float4*)b1;
    const float4* f4 = (const float4*)(feats + (size_t)i * 64);

    float4 f[16];
#pragma unroll
    for (int q = 0; q < 16; ++q)
        f[q] = valid ? f4[q] : make_float4(0.f, 0.f, 0.f, 0.f);

#pragma unroll 1  // keep code small (I$); inner q-loop fully unrolled
    for (int cg = 0; cg < 16; ++cg) {
        float4 acc = b4[cg];
#pragma unroll
        for (int q = 0; q < 16; ++q) {
            float4 fq = f[q];
            float4 wa = w4[(cg * 4 + 0) * 16 + q];
            float4 wb = w4[(cg * 4 + 1) * 16 + q];
            float4 wc = w4[(cg * 4 + 2) * 16 + q];
            float4 wd = w4[(cg * 4 + 3) * 16 + q];
            acc.x += fq.x * wa.x + fq.y * wa.y + fq.z * wa.z + fq.w * wa.w;
            acc.y += fq.x * wb.x + fq.y * wb.y + fq.z * wb.z + fq.w * wb.w;
            acc.z += fq.x * wc.x + fq.y * wc.y + fq.z * wc.z + fq.w * wc.w;
            acc.w += fq.x * wd.x + fq.y * wd.y + fq.z * wd.z + fq.w * wd.w;
        }
        if (valid) *(float4*)(h + (size_t)i * 64 + cg * 4) = acc;
    }

    int nl = n - base; if (nl > 64) nl = 64;
    // pair fixup: wave-cooperative, one pair at a time (lane = out channel)
#pragma unroll 1
    for (int l = 0; l < nl; ++l) {
        int row = base + l;
        int cnt = c1[row];  // wave-uniform
#pragma unroll 1
        for (int tt = 0; tt < cnt; ++tt) {
            int e = p1[row * CAP1 + tt];  // wave-uniform
            int j = e & 0xFFFFF, k = e >> 20;
            const float* wk = W1 + (size_t)k * 4096;  // [ci][co]
            const float* fj = feats + (size_t)j * 64;
            float contrib = 0.f;
#pragma unroll
            for (int c4 = 0; c4 < 16; ++c4) {
                float4 fv = *(const float4*)(fj + c4 * 4);  // uniform
                contrib += fv.x * wk[(c4 * 4 + 0) * 64 + lane];
                contrib += fv.y * wk[(c4 * 4 + 1) * 64 + lane];
                contrib += fv.z * wk[(c4 * 4 + 2) * 64 + lane];
                contrib += fv.w * wk[(c4 * 4 + 3) * 64 + lane];
            }
            h[(size_t)row * 64 + lane] += contrib;  // row owned by this wave
        }
    }
    // SiLU epilogue (rows complete; coalesced per row)
#pragma unroll 1
    for (int l = 0; l < nl; ++l) {
        size_t idx = (size_t)(base + l) * 64 + lane;
        float v = h[idx];
        h[idx] = v / (1.f + __expf(-v));
    }
}

// ---------------------------------------------------------------------------
// conv2 fused: grid (chunks, 8). Block handles 64 parents for one child s:
// dense center slot + per-pair fixup (filtered by s) + SiLU. Writes final out.
// ---------------------------------------------------------------------------
__global__ __launch_bounds__(64, 2) void conv2_fused_kernel(
    const float* __restrict__ h, const float* __restrict__ W2Tc,
    const float* __restrict__ W2e, const float* __restrict__ b2,
    const int* __restrict__ c2, const int* __restrict__ p2,
    float* __restrict__ out, int n) {
    int pbase = blockIdx.x * 64, lane = threadIdx.x;
    int s = blockIdx.y;
    int p = pbase + lane;
    bool valid = p < n;
    const float4* w4 = (const float4*)(W2Tc + (size_t)s * 4096);
    const float4* b4 = (const float4*)b2;
    const float4* f4 = (const float4*)(h + (size_t)p * 64);

    float4 f[16];
#pragma unroll
    for (int q = 0; q < 16; ++q)
        f[q] = valid ? f4[q] : make_float4(0.f, 0.f, 0.f, 0.f);

#pragma unroll 1
    for (int cg = 0; cg < 16; ++cg) {
        float4 acc = b4[cg];
#pragma unroll
        for (int q = 0; q < 16; ++q) {
            float4 fq = f[q];
            float4 wa = w4[(cg * 4 + 0) * 16 + q];
            float4 wb = w4[(cg * 4 + 1) * 16 + q];
            float4 wc = w4[(cg * 4 + 2) * 16 + q];
            float4 wd = w4[(cg * 4 + 3) * 16 + q];
            acc.x += fq.x * wa.x + fq.y * wa.y + fq.z * wa.z + fq.w * wa.w;
            acc.y += fq.x * wb.x + fq.y * wb.y + fq.z * wb.z + fq.w * wb.w;
            acc.z += fq.x * wc.x + fq.y * wc.y + fq.z * wc.z + fq.w * wc.w;
            acc.w += fq.x * wd.x + fq.y * wd.y + fq.z * wd.z + fq.w * wd.w;
        }
        if (valid)
            *(float4*)(out + ((size_t)p * 8 + s) * 64 + cg * 4) = acc;
    }

    int nl = n - pbase; if (nl > 64) nl = 64;
#pragma unroll 1
    for (int l = 0; l < nl; ++l) {
        int pp = pbase + l;
        int cnt = c2[pp];  // wave-uniform
#pragma unroll 1
        for (int tt = 0; tt < cnt; ++tt) {
            int e = p2[pp * CAP2 + tt];  // wave-uniform
            int sd = e >> 20;
            if ((sd >> 3) != s) continue;  // this block owns child s only
            int j = e & 0xFFFFF;
            const float* wk = W2e + (size_t)sd * 4096;  // [ci][co]
            const float* fj = h + (size_t)j * 64;
            float contrib = 0.f;
#pragma unroll
            for (int c4 = 0; c4 < 16; ++c4) {
                float4 fv = *(const float4*)(fj + c4 * 4);  // uniform
                contrib += fv.x * wk[(c4 * 4 + 0) * 64 + lane];
                contrib += fv.y * wk[(c4 * 4 + 1) * 64 + lane];
                contrib += fv.z * wk[(c4 * 4 + 2) * 64 + lane];
                contrib += fv.w * wk[(c4 * 4 + 3) * 64 + lane];
            }
            out[((size_t)pp * 8 + s) * 64 + lane] += contrib;
        }
    }
#pragma unroll 1
    for (int l = 0; l < nl; ++l) {
        size_t idx = ((size_t)(pbase + l) * 8 + s) * 64 + lane;
        float v = out[idx];
        out[idx] = v / (1.f + __expf(-v));
    }
}

// ---------------------------------------------------------------------------
extern "C" void kernel_launch(void* const* d_in, const int* in_sizes, int n_in,
                              void* d_out, int out_size, void* d_ws,
                              size_t ws_size, hipStream_t stream) {
    const int* coords = (const int*)d_in[0];
    const float* feats = (const float*)d_in[1];
    const float* W1 = (const float*)d_in[2];
    const float* b1 = (const float*)d_in[3];
    const float* W2 = (const float*)d_in[4];
    const float* b2 = (const float*)d_in[5];
    float* out = (float*)d_out;

    int n = in_sizes[0] / 3;  // 20000

    char* ws = (char*)d_ws;
    size_t off = 0;
    auto alloc = [&](size_t bytes) {
        size_t o = off;
        off = (off + bytes + 255) & ~(size_t)255;
        return o;
    };
    int*   grid1 = (int*)(ws + alloc((size_t)GRID_VOX * 4));      // 3.54 MB
    float* h     = (float*)(ws + alloc((size_t)n * 64 * 4));      // 5.12 MB
    float* W1T13 = (float*)(ws + alloc(4096 * 4));                // 16 KB
    float* W2Tc  = (float*)(ws + alloc(8 * 4096 * 4));            // 128 KB
    float* W2e   = (float*)(ws + alloc(64 * 4096 * 4));           // 1 MB
    int*   c1    = (int*)(ws + alloc((size_t)n * 4 * 2));         // c1+c2 contiguous
    int*   c2    = c1 + n;
    int*   p1    = (int*)(ws + alloc((size_t)n * CAP1 * 4));      // 2.56 MB
    int*   p2    = (int*)(ws + alloc((size_t)n * CAP2 * 4));      // 5.12 MB

    hipMemsetAsync(grid1, 0xFF, (size_t)GRID_VOX * 4, stream);
    hipMemsetAsync(c1, 0, (size_t)n * 4 * 2, stream);

    scatter_grid_kernel<<<(n + 255) / 256, 256, 0, stream>>>(coords, grid1, n);
    prep_weights_kernel<<<73 * 16, 256, 0, stream>>>(W1, W2, W1T13, W2Tc, W2e);
    build_pairs_kernel<<<(n * 27 + 255) / 256, 256, 0, stream>>>(
        coords, grid1, c1, p1, c2, p2, n);

    int nblk = (n + 63) / 64;
    conv1_fused_kernel<<<nblk, 64, 0, stream>>>(feats, W1, W1T13, b1, c1, p1, h, n);
    conv2_fused_kernel<<<dim3(nblk, 8), 64, 0, stream>>>(h, W2Tc, W2e, b2, c2, p2,
                                                         out, n);
}

// Round 4
// 237.561 us; speedup vs baseline: 2.5427x; 1.0391x over previous
//
#include <hip/hip_runtime.h>

#define D1 96
#define GRID_VOX (D1 * D1 * D1)
#define CAP1 32   // per-parent conv1 pairs (max 26 exact)
#define CAP2S 16  // per-(parent,s) conv2 pairs (max 26 theoretical, ~3 typical)

// ---------------------------------------------------------------------------
__global__ void scatter_grid_kernel(const int* __restrict__ coords,
                                    int* __restrict__ grid, int n) {
    int i = blockIdx.x * blockDim.x + threadIdx.x;
    if (i < n)
        grid[(coords[3 * i] * D1 + coords[3 * i + 1]) * D1 + coords[3 * i + 2]] = i;
}

// ---------------------------------------------------------------------------
// W1T13[co*64+ci] = W1[13][ci][co]                      (4096)
// W2Tc[s][co*64+ci] = sum_{self-parent taps} W2[k][ci][co]  (8*4096)
// W2e[sd][ci*64+co] = sum_{taps->sd} W2[k][ci][co]      (64*4096, orig layout)
// ---------------------------------------------------------------------------
__global__ void prep_weights_kernel(const float* __restrict__ W1,
                                    const float* __restrict__ W2,
                                    float* __restrict__ W1T13,
                                    float* __restrict__ W2Tc,
                                    float* __restrict__ W2e) {
    int t = blockIdx.x * blockDim.x + threadIdx.x;
    if (t >= 73 * 4096) return;
    if (t < 4096) {
        int co = t >> 6, ci = t & 63;
        W1T13[t] = W1[13 * 4096 + ci * 64 + co];
    } else if (t < 9 * 4096) {
        int r = t - 4096;
        int s = r >> 12, e = r & 4095;
        int co = e >> 6, ci = e & 63;
        int sa[3] = { (s >> 2) & 1, (s >> 1) & 1, s & 1 };
        float sum = 0.f;
        for (int o0 = -sa[0]; o0 <= 1 - sa[0]; ++o0)
            for (int o1 = -sa[1]; o1 <= 1 - sa[1]; ++o1)
                for (int o2 = -sa[2]; o2 <= 1 - sa[2]; ++o2) {
                    int k = (o0 + 1) * 9 + (o1 + 1) * 3 + (o2 + 1);
                    sum += W2[k * 4096 + ci * 64 + co];
                }
        W2Tc[s * 4096 + co * 64 + ci] = sum;
    } else {
        int r = t - 9 * 4096;
        int sd = r >> 12, e = r & 4095;  // e = ci*64+co
        int s = sd >> 3, d = sd & 7;
        int sa[3] = { (s >> 2) & 1, (s >> 1) & 1, s & 1 };
        int da[3] = { (d >> 2) & 1, (d >> 1) & 1, d & 1 };
        int lo[3], hi[3];
        for (int a = 0; a < 3; ++a) {
            int p = sa[a] - 1 + da[a];
            int l = 2 * p - sa[a];     if (l < -1) l = -1;
            int h = 2 * p + 1 - sa[a]; if (h > 1) h = 1;
            lo[a] = l; hi[a] = h;
        }
        float sum = 0.f;
        for (int o0 = lo[0]; o0 <= hi[0]; ++o0)
            for (int o1 = lo[1]; o1 <= hi[1]; ++o1)
                for (int o2 = lo[2]; o2 <= hi[2]; ++o2) {
                    int k = (o0 + 1) * 9 + (o1 + 1) * 3 + (o2 + 1);
                    sum += W2[k * 4096 + e];
                }
        W2e[sd * 4096 + e] = sum;
    }
}

// ---------------------------------------------------------------------------
// Pair lists: conv1 per parent i (tag k); conv2 per (i,s) bucket (tag d).
// ---------------------------------------------------------------------------
__global__ void build_pairs_kernel(const int* __restrict__ coords,
                                   const int* __restrict__ grid,
                                   int* __restrict__ c1, int* __restrict__ p1,
                                   int* __restrict__ c2s, int* __restrict__ p2s,
                                   int n) {
    int t = blockIdx.x * blockDim.x + threadIdx.x;
    if (t >= n * 27) return;
    int i = t / 27, k = t % 27;
    if (k == 13) return;  // self tap handled dense
    int o[3] = { k / 9 - 1, (k / 3) % 3 - 1, k % 3 - 1 };
    int x0 = coords[3 * i] + o[0];
    int x1 = coords[3 * i + 1] + o[1];
    int x2 = coords[3 * i + 2] + o[2];
    if ((unsigned)x0 >= D1 || (unsigned)x1 >= D1 || (unsigned)x2 >= D1) return;
    int j = grid[(x0 * D1 + x1) * D1 + x2];
    if (j < 0) return;

    int s1 = atomicAdd(&c1[i], 1);
    if (s1 < CAP1) p1[i * CAP1 + s1] = j | (k << 20);

    // per axis: o=-1 ->(s,d)=(0,0); o=0 ->(0,1),(1,0); o=1 ->(1,1)
    int cnt[3], sop[3][2], dop[3][2];
#pragma unroll
    for (int a = 0; a < 3; ++a) {
        if (o[a] == -1)     { cnt[a] = 1; sop[a][0] = 0; dop[a][0] = 0; }
        else if (o[a] == 0) { cnt[a] = 2; sop[a][0] = 0; dop[a][0] = 1;
                                          sop[a][1] = 1; dop[a][1] = 0; }
        else                { cnt[a] = 1; sop[a][0] = 1; dop[a][0] = 1; }
    }
    for (int a0 = 0; a0 < cnt[0]; ++a0)
        for (int a1 = 0; a1 < cnt[1]; ++a1)
            for (int a2 = 0; a2 < cnt[2]; ++a2) {
                int s = (sop[0][a0] << 2) | (sop[1][a1] << 1) | sop[2][a2];
                int d = (dop[0][a0] << 2) | (dop[1][a1] << 1) | dop[2][a2];
                int b = i * 8 + s;
                int sl = atomicAdd(&c2s[b], 1);
                if (sl < CAP2S) p2s[b * CAP2S + sl] = j | (d << 20);
            }
}

// ---------------------------------------------------------------------------
// conv1 fused: dense self-tap (lane=row, SGPR weights) -> LDS tile; fixups
// accumulate into LDS (wave-coop, lane=co); SiLU; one coalesced store.
// ---------------------------------------------------------------------------
__global__ __launch_bounds__(64) void conv1_fused_kernel(
    const float* __restrict__ feats, const float* __restrict__ W1,
    const float* __restrict__ W1T13, const float* __restrict__ b1,
    const int* __restrict__ c1, const int* __restrict__ p1,
    float* __restrict__ h, int n) {
    __shared__ float lds[64 * 65];
    int base = blockIdx.x * 64, lane = threadIdx.x;
    int i = base + lane;
    bool valid = i < n;

    float4 f[16];
    const float4* f4 = (const float4*)(feats + (size_t)(valid ? i : 0) * 64);
#pragma unroll
    for (int q = 0; q < 16; ++q)
        f[q] = valid ? f4[q] : make_float4(0.f, 0.f, 0.f, 0.f);

    const float4* w4 = (const float4*)W1T13;
    const float4* b4 = (const float4*)b1;
#pragma unroll 1
    for (int cg = 0; cg < 16; ++cg) {
        float4 acc = b4[cg];
#pragma unroll
        for (int q = 0; q < 16; ++q) {
            float4 fq = f[q];
            float4 wa = w4[(cg * 4 + 0) * 16 + q];
            float4 wb = w4[(cg * 4 + 1) * 16 + q];
            float4 wc = w4[(cg * 4 + 2) * 16 + q];
            float4 wd = w4[(cg * 4 + 3) * 16 + q];
            acc.x += fq.x * wa.x + fq.y * wa.y + fq.z * wa.z + fq.w * wa.w;
            acc.y += fq.x * wb.x + fq.y * wb.y + fq.z * wb.z + fq.w * wb.w;
            acc.z += fq.x * wc.x + fq.y * wc.y + fq.z * wc.z + fq.w * wc.w;
            acc.w += fq.x * wd.x + fq.y * wd.y + fq.z * wd.z + fq.w * wd.w;
        }
        *(float4*)&lds[lane * 65 + cg * 4] = acc;
    }

    // fixups into LDS
    int cnt = valid ? c1[i] : 0;
    unsigned long long mask = __ballot(cnt > 0);
    while (mask) {
        int l = __ffsll(mask) - 1;
        mask &= mask - 1;
        int cl = __shfl(cnt, l);
        const int* plist = p1 + (size_t)(base + l) * CAP1;
        for (int tt = 0; tt < cl; ++tt) {
            int e = plist[tt];  // wave-uniform
            int j = e & 0xFFFFF, k = e >> 20;
            const float* wk = W1 + (size_t)k * 4096;  // [ci][co]
            float hj = feats[(size_t)j * 64 + lane];
            float a0 = 0.f, a1 = 0.f, a2 = 0.f, a3 = 0.f;
#pragma unroll
            for (int ci = 0; ci < 64; ci += 4) {
                a0 += __shfl(hj, ci + 0) * wk[(ci + 0) * 64 + lane];
                a1 += __shfl(hj, ci + 1) * wk[(ci + 1) * 64 + lane];
                a2 += __shfl(hj, ci + 2) * wk[(ci + 2) * 64 + lane];
                a3 += __shfl(hj, ci + 3) * wk[(ci + 3) * 64 + lane];
            }
            lds[l * 65 + lane] += (a0 + a1) + (a2 + a3);
        }
    }

    // SiLU + coalesced store
    int nl = n - base; if (nl > 64) nl = 64;
#pragma unroll
    for (int jj = 0; jj < 16; ++jj) {
        int flat = jj * 256 + lane * 4;
        int r = flat >> 6, c = flat & 63;
        if (r < nl) {
            float4 v = *(float4*)&lds[r * 65 + c];
            v.x = v.x / (1.f + __expf(-v.x));
            v.y = v.y / (1.f + __expf(-v.y));
            v.z = v.z / (1.f + __expf(-v.z));
            v.w = v.w / (1.f + __expf(-v.w));
            *(float4*)&h[(size_t)(base + r) * 64 + c] = v;
        }
    }
}

// ---------------------------------------------------------------------------
// conv2 fused: grid (chunks, 8 children). Same structure; per-(i,s) buckets.
// ---------------------------------------------------------------------------
__global__ __launch_bounds__(64) void conv2_fused_kernel(
    const float* __restrict__ h, const float* __restrict__ W2Tc,
    const float* __restrict__ W2e, const float* __restrict__ b2,
    const int* __restrict__ c2s, const int* __restrict__ p2s,
    float* __restrict__ out, int n) {
    __shared__ float lds[64 * 65];
    int base = blockIdx.x * 64, lane = threadIdx.x;
    int s = blockIdx.y;
    int p = base + lane;
    bool valid = p < n;

    float4 f[16];
    const float4* f4 = (const float4*)(h + (size_t)(valid ? p : 0) * 64);
#pragma unroll
    for (int q = 0; q < 16; ++q)
        f[q] = valid ? f4[q] : make_float4(0.f, 0.f, 0.f, 0.f);

    const float4* w4 = (const float4*)(W2Tc + (size_t)s * 4096);
    const float4* b4 = (const float4*)b2;
#pragma unroll 1
    for (int cg = 0; cg < 16; ++cg) {
        float4 acc = b4[cg];
#pragma unroll
        for (int q = 0; q < 16; ++q) {
            float4 fq = f[q];
            float4 wa = w4[(cg * 4 + 0) * 16 + q];
            float4 wb = w4[(cg * 4 + 1) * 16 + q];
            float4 wc = w4[(cg * 4 + 2) * 16 + q];
            float4 wd = w4[(cg * 4 + 3) * 16 + q];
            acc.x += fq.x * wa.x + fq.y * wa.y + fq.z * wa.z + fq.w * wa.w;
            acc.y += fq.x * wb.x + fq.y * wb.y + fq.z * wb.z + fq.w * wb.w;
            acc.z += fq.x * wc.x + fq.y * wc.y + fq.z * wc.z + fq.w * wc.w;
            acc.w += fq.x * wd.x + fq.y * wd.y + fq.z * wd.z + fq.w * wd.w;
        }
        *(float4*)&lds[lane * 65 + cg * 4] = acc;
    }

    int cnt = valid ? c2s[p * 8 + s] : 0;
    if (cnt > CAP2S) cnt = CAP2S;
    unsigned long long mask = __ballot(cnt > 0);
    while (mask) {
        int l = __ffsll(mask) - 1;
        mask &= mask - 1;
        int cl = __shfl(cnt, l);
        const int* plist = p2s + ((size_t)(base + l) * 8 + s) * CAP2S;
        for (int tt = 0; tt < cl; ++tt) {
            int e = plist[tt];  // wave-uniform
            int j = e & 0xFFFFF, d = e >> 20;
            const float* wk = W2e + (size_t)(s * 8 + d) * 4096;  // [ci][co]
            float hj = h[(size_t)j * 64 + lane];
            float a0 = 0.f, a1 = 0.f, a2 = 0.f, a3 = 0.f;
#pragma unroll
            for (int ci = 0; ci < 64; ci += 4) {
                a0 += __shfl(hj, ci + 0) * wk[(ci + 0) * 64 + lane];
                a1 += __shfl(hj, ci + 1) * wk[(ci + 1) * 64 + lane];
                a2 += __shfl(hj, ci + 2) * wk[(ci + 2) * 64 + lane];
                a3 += __shfl(hj, ci + 3) * wk[(ci + 3) * 64 + lane];
            }
            lds[l * 65 + lane] += (a0 + a1) + (a2 + a3);
        }
    }

    int nl = n - base; if (nl > 64) nl = 64;
#pragma unroll
    for (int jj = 0; jj < 16; ++jj) {
        int flat = jj * 256 + lane * 4;
        int r = flat >> 6, c = flat & 63;
        if (r < nl) {
            float4 v = *(float4*)&lds[r * 65 + c];
            v.x = v.x / (1.f + __expf(-v.x));
            v.y = v.y / (1.f + __expf(-v.y));
            v.z = v.z / (1.f + __expf(-v.z));
            v.w = v.w / (1.f + __expf(-v.w));
            *(float4*)&out[((size_t)(base + r) * 8 + s) * 64 + c] = v;
        }
    }
}

// ---------------------------------------------------------------------------
extern "C" void kernel_launch(void* const* d_in, const int* in_sizes, int n_in,
                              void* d_out, int out_size, void* d_ws,
                              size_t ws_size, hipStream_t stream) {
    const int* coords = (const int*)d_in[0];
    const float* feats = (const float*)d_in[1];
    const float* W1 = (const float*)d_in[2];
    const float* b1 = (const float*)d_in[3];
    const float* W2 = (const float*)d_in[4];
    const float* b2 = (const float*)d_in[5];
    float* out = (float*)d_out;

    int n = in_sizes[0] / 3;  // 20000

    char* ws = (char*)d_ws;
    size_t off = 0;
    auto alloc = [&](size_t bytes) {
        size_t o = off;
        off = (off + bytes + 255) & ~(size_t)255;
        return o;
    };
    int*   grid1 = (int*)(ws + alloc((size_t)GRID_VOX * 4));        // 3.54 MB
    float* h     = (float*)(ws + alloc((size_t)n * 64 * 4));        // 5.12 MB
    float* W1T13 = (float*)(ws + alloc(4096 * 4));                  // 16 KB
    float* W2Tc  = (float*)(ws + alloc(8 * 4096 * 4));              // 128 KB
    float* W2e   = (float*)(ws + alloc(64 * 4096 * 4));             // 1 MB
    int*   c1    = (int*)(ws + alloc((size_t)n * 9 * 4));           // c1[n]+c2s[8n]
    int*   c2s   = c1 + n;
    int*   p1    = (int*)(ws + alloc((size_t)n * CAP1 * 4));        // 2.56 MB
    int*   p2s   = (int*)(ws + alloc((size_t)n * 8 * CAP2S * 4));   // 10.2 MB

    hipMemsetAsync(grid1, 0xFF, (size_t)GRID_VOX * 4, stream);
    hipMemsetAsync(c1, 0, (size_t)n * 9 * 4, stream);

    scatter_grid_kernel<<<(n + 255) / 256, 256, 0, stream>>>(coords, grid1, n);
    prep_weights_kernel<<<73 * 16, 256, 0, stream>>>(W1, W2, W1T13, W2Tc, W2e);
    build_pairs_kernel<<<(n * 27 + 255) / 256, 256, 0, stream>>>(
        coords, grid1, c1, p1, c2s, p2s, n);

    int nblk = (n + 63) / 64;
    conv1_fused_kernel<<<nblk, 64, 0, stream>>>(feats, W1, W1T13, b1, c1, p1, h, n);
    conv2_fused_kernel<<<dim3(nblk, 8), 64, 0, stream>>>(h, W2Tc, W2e, b2,
                                                         c2s, p2s, out, n);
}

// Round 5
// 208.200 us; speedup vs baseline: 2.9012x; 1.1410x over previous
//
#include <hip/hip_runtime.h>

#define D1 96
#define GRID_VOX (D1 * D1 * D1)
#define CAP1 32   // per-parent conv1 pairs (max 26 exact)
#define CAP2S 8   // per-(parent,s) conv2 pairs (max 7 exact)

// ---------------------------------------------------------------------------
__global__ void scatter_grid_kernel(const int* __restrict__ coords,
                                    int* __restrict__ grid, int n) {
    int i = blockIdx.x * blockDim.x + threadIdx.x;
    if (i < n)
        grid[(coords[3 * i] * D1 + coords[3 * i + 1]) * D1 + coords[3 * i + 2]] = i;
}

// ---------------------------------------------------------------------------
// W1T13[co*64+ci] = W1[13][ci][co]                          (4096)
// W2Tc[s][co*64+ci] = sum_{self-parent taps} W2[k][ci][co]  (8*4096)
// W2e[sd][ci*64+co] = sum_{taps->sd} W2[k][ci][co]          (64*4096, orig layout)
// ---------------------------------------------------------------------------
__global__ void prep_weights_kernel(const float* __restrict__ W1,
                                    const float* __restrict__ W2,
                                    float* __restrict__ W1T13,
                                    float* __restrict__ W2Tc,
                                    float* __restrict__ W2e) {
    int t = blockIdx.x * blockDim.x + threadIdx.x;
    if (t >= 73 * 4096) return;
    if (t < 4096) {
        int co = t >> 6, ci = t & 63;
        W1T13[t] = W1[13 * 4096 + ci * 64 + co];
    } else if (t < 9 * 4096) {
        int r = t - 4096;
        int s = r >> 12, e = r & 4095;
        int co = e >> 6, ci = e & 63;
        int sa[3] = { (s >> 2) & 1, (s >> 1) & 1, s & 1 };
        float sum = 0.f;
        for (int o0 = -sa[0]; o0 <= 1 - sa[0]; ++o0)
            for (int o1 = -sa[1]; o1 <= 1 - sa[1]; ++o1)
                for (int o2 = -sa[2]; o2 <= 1 - sa[2]; ++o2) {
                    int k = (o0 + 1) * 9 + (o1 + 1) * 3 + (o2 + 1);
                    sum += W2[k * 4096 + ci * 64 + co];
                }
        W2Tc[s * 4096 + co * 64 + ci] = sum;
    } else {
        int r = t - 9 * 4096;
        int sd = r >> 12, e = r & 4095;  // e = ci*64+co
        int s = sd >> 3, d = sd & 7;
        int sa[3] = { (s >> 2) & 1, (s >> 1) & 1, s & 1 };
        int da[3] = { (d >> 2) & 1, (d >> 1) & 1, d & 1 };
        int lo[3], hi[3];
        for (int a = 0; a < 3; ++a) {
            int p = sa[a] - 1 + da[a];
            int l = 2 * p - sa[a];     if (l < -1) l = -1;
            int h = 2 * p + 1 - sa[a]; if (h > 1) h = 1;
            lo[a] = l; hi[a] = h;
        }
        float sum = 0.f;
        for (int o0 = lo[0]; o0 <= hi[0]; ++o0)
            for (int o1 = lo[1]; o1 <= hi[1]; ++o1)
                for (int o2 = lo[2]; o2 <= hi[2]; ++o2) {
                    int k = (o0 + 1) * 9 + (o1 + 1) * 3 + (o2 + 1);
                    sum += W2[k * 4096 + e];
                }
        W2e[sd * 4096 + e] = sum;
    }
}

// ---------------------------------------------------------------------------
// Per-voxel pair builder (no atomics; each thread owns its buckets).
// conv1: p1[i*CAP1 + t] = j | (k<<20)
// conv2: p2s[(i*8+s)*CAP2S + t] = j | (d<<20)   (per-axis d = o+1-s, valid in {0,1})
// ---------------------------------------------------------------------------
__global__ void build_pairs_kernel(const int* __restrict__ coords,
                                   const int* __restrict__ grid,
                                   int* __restrict__ c1, int* __restrict__ p1,
                                   int* __restrict__ c2s, int* __restrict__ p2s,
                                   int n) {
    int i = blockIdx.x * blockDim.x + threadIdx.x;
    if (i >= n) return;
    int c0 = coords[3 * i], cc1 = coords[3 * i + 1], cc2 = coords[3 * i + 2];
    int n1 = 0;
    int n2[8] = {0, 0, 0, 0, 0, 0, 0, 0};
#pragma unroll 1
    for (int k = 0; k < 27; ++k) {
        if (k == 13) continue;
        int o0 = k / 9 - 1, o1 = (k / 3) % 3 - 1, o2 = k % 3 - 1;
        int x0 = c0 + o0, x1 = cc1 + o1, x2 = cc2 + o2;
        if ((unsigned)x0 >= D1 || (unsigned)x1 >= D1 || (unsigned)x2 >= D1)
            continue;
        int j = grid[(x0 * D1 + x1) * D1 + x2];
        if (j < 0) continue;
        p1[(size_t)i * CAP1 + n1] = j | (k << 20);
        ++n1;
#pragma unroll
        for (int s = 0; s < 8; ++s) {
            int d0 = o0 + 1 - ((s >> 2) & 1);
            int d1 = o1 + 1 - ((s >> 1) & 1);
            int d2 = o2 + 1 - (s & 1);
            if (((d0 | d1 | d2) & ~1) == 0) {
                int d = (d0 << 2) | (d1 << 1) | d2;
                p2s[((size_t)i * 8 + s) * CAP2S + n2[s]] = j | (d << 20);
                ++n2[s];
            }
        }
    }
    c1[i] = n1;
#pragma unroll
    for (int s = 0; s < 8; ++s) c2s[i * 8 + s] = n2[s];
}

// ---------------------------------------------------------------------------
// conv1 fused: 256 threads = 4 waves on one 64-row tile.
// stage fT (coalesced) -> dense (wave w owns col-groups 4w..4w+3, lane=row,
// f from LDS, uniform weights) -> fixups (rows split by wave, lane=co) ->
// SiLU + coalesced store.
// ---------------------------------------------------------------------------
__global__ __launch_bounds__(256) void conv1_fused_kernel(
    const float* __restrict__ feats, const float* __restrict__ W1,
    const float* __restrict__ W1T13, const float* __restrict__ b1,
    const int* __restrict__ c1, const int* __restrict__ p1,
    float* __restrict__ h, int n) {
    __shared__ float fT[64 * 65];
    __shared__ float oT[64 * 65];
    int base = blockIdx.x * 64;
    int t = threadIdx.x, w = t >> 6, lane = t & 63;

    {   // stage f-tile: thread t -> row t>>2, 16-float chunk t&3
        int r = t >> 2, qq = t & 3;
        bool v = (base + r) < n;
        const float4* src = (const float4*)(feats + (size_t)(base + r) * 64 + qq * 16);
        float4 z = make_float4(0.f, 0.f, 0.f, 0.f);
#pragma unroll
        for (int j = 0; j < 4; ++j)
            *(float4*)&fT[r * 65 + qq * 16 + j * 4] = v ? src[j] : z;
    }
    __syncthreads();

    float4 f[16];
#pragma unroll
    for (int q = 0; q < 16; ++q) f[q] = *(float4*)&fT[lane * 65 + q * 4];

    const float4* wbase = (const float4*)W1T13;
    const float4* b4 = (const float4*)b1;
#pragma unroll 1
    for (int c = 0; c < 4; ++c) {
        int cg = w * 4 + c;
        float4 acc = b4[cg];
        const float4* w4 = wbase + (size_t)cg * 64;
#pragma unroll
        for (int q = 0; q < 16; ++q) {
            float4 fq = f[q];
            float4 wa = w4[q], wb = w4[16 + q], wc = w4[32 + q], wd = w4[48 + q];
            acc.x += fq.x * wa.x + fq.y * wa.y + fq.z * wa.z + fq.w * wa.w;
            acc.y += fq.x * wb.x + fq.y * wb.y + fq.z * wb.z + fq.w * wb.w;
            acc.z += fq.x * wc.x + fq.y * wc.y + fq.z * wc.z + fq.w * wc.w;
            acc.w += fq.x * wd.x + fq.y * wd.y + fq.z * wd.z + fq.w * wd.w;
        }
        *(float4*)&oT[lane * 65 + cg * 4] = acc;
    }
    __syncthreads();

    // fixups: rows with (l & 3) == w handled by wave w (race-free)
    int cnt = (base + lane < n) ? c1[base + lane] : 0;
    unsigned long long mask = __ballot(cnt > 0 && (lane & 3) == w);
    while (mask) {
        int l = __ffsll(mask) - 1;
        mask &= mask - 1;
        int cl = __shfl(cnt, l);
        const int* plist = p1 + (size_t)(base + l) * CAP1;
        for (int tt = 0; tt < cl; ++tt) {
            int e = plist[tt];  // wave-uniform
            int j = e & 0xFFFFF, k = e >> 20;
            const float* wk = W1 + (size_t)k * 4096;  // [ci][co]
            float hj = feats[(size_t)j * 64 + lane];
            float a0 = 0.f, a1 = 0.f, a2 = 0.f, a3 = 0.f;
#pragma unroll
            for (int ci = 0; ci < 64; ci += 4) {
                a0 += __shfl(hj, ci + 0) * wk[(ci + 0) * 64 + lane];
                a1 += __shfl(hj, ci + 1) * wk[(ci + 1) * 64 + lane];
                a2 += __shfl(hj, ci + 2) * wk[(ci + 2) * 64 + lane];
                a3 += __shfl(hj, ci + 3) * wk[(ci + 3) * 64 + lane];
            }
            oT[l * 65 + lane] += (a0 + a1) + (a2 + a3);
        }
    }
    __syncthreads();

    {   // SiLU + coalesced store
        int r = t >> 2, qq = t & 3;
        if (base + r < n) {
#pragma unroll
            for (int j = 0; j < 4; ++j) {
                float4 v = *(float4*)&oT[r * 65 + qq * 16 + j * 4];
                v.x = v.x / (1.f + __expf(-v.x));
                v.y = v.y / (1.f + __expf(-v.y));
                v.z = v.z / (1.f + __expf(-v.z));
                v.w = v.w / (1.f + __expf(-v.w));
                *(float4*)&h[(size_t)(base + r) * 64 + qq * 16 + j * 4] = v;
            }
        }
    }
}

// ---------------------------------------------------------------------------
// conv2 fused: grid (chunks, 8 children). Same 4-wave structure.
// ---------------------------------------------------------------------------
__global__ __launch_bounds__(256) void conv2_fused_kernel(
    const float* __restrict__ h, const float* __restrict__ W2Tc,
    const float* __restrict__ W2e, const float* __restrict__ b2,
    const int* __restrict__ c2s, const int* __restrict__ p2s,
    float* __restrict__ out, int n) {
    __shared__ float fT[64 * 65];
    __shared__ float oT[64 * 65];
    int base = blockIdx.x * 64;
    int s = blockIdx.y;
    int t = threadIdx.x, w = t >> 6, lane = t & 63;

    {   // stage f-tile
        int r = t >> 2, qq = t & 3;
        bool v = (base + r) < n;
        const float4* src = (const float4*)(h + (size_t)(base + r) * 64 + qq * 16);
        float4 z = make_float4(0.f, 0.f, 0.f, 0.f);
#pragma unroll
        for (int j = 0; j < 4; ++j)
            *(float4*)&fT[r * 65 + qq * 16 + j * 4] = v ? src[j] : z;
    }
    __syncthreads();

    float4 f[16];
#pragma unroll
    for (int q = 0; q < 16; ++q) f[q] = *(float4*)&fT[lane * 65 + q * 4];

    const float4* wbase = (const float4*)(W2Tc + (size_t)s * 4096);
    const float4* b4 = (const float4*)b2;
#pragma unroll 1
    for (int c = 0; c < 4; ++c) {
        int cg = w * 4 + c;
        float4 acc = b4[cg];
        const float4* w4 = wbase + (size_t)cg * 64;
#pragma unroll
        for (int q = 0; q < 16; ++q) {
            float4 fq = f[q];
            float4 wa = w4[q], wb = w4[16 + q], wc = w4[32 + q], wd = w4[48 + q];
            acc.x += fq.x * wa.x + fq.y * wa.y + fq.z * wa.z + fq.w * wa.w;
            acc.y += fq.x * wb.x + fq.y * wb.y + fq.z * wb.z + fq.w * wb.w;
            acc.z += fq.x * wc.x + fq.y * wc.y + fq.z * wc.z + fq.w * wc.w;
            acc.w += fq.x * wd.x + fq.y * wd.y + fq.z * wd.z + fq.w * wd.w;
        }
        *(float4*)&oT[lane * 65 + cg * 4] = acc;
    }
    __syncthreads();

    int cnt = (base + lane < n) ? c2s[(size_t)(base + lane) * 8 + s] : 0;
    unsigned long long mask = __ballot(cnt > 0 && (lane & 3) == w);
    while (mask) {
        int l = __ffsll(mask) - 1;
        mask &= mask - 1;
        int cl = __shfl(cnt, l);
        const int* plist = p2s + ((size_t)(base + l) * 8 + s) * CAP2S;
        for (int tt = 0; tt < cl; ++tt) {
            int e = plist[tt];  // wave-uniform
            int j = e & 0xFFFFF, d = e >> 20;
            const float* wk = W2e + (size_t)(s * 8 + d) * 4096;  // [ci][co]
            float hj = h[(size_t)j * 64 + lane];
            float a0 = 0.f, a1 = 0.f, a2 = 0.f, a3 = 0.f;
#pragma unroll
            for (int ci = 0; ci < 64; ci += 4) {
                a0 += __shfl(hj, ci + 0) * wk[(ci + 0) * 64 + lane];
                a1 += __shfl(hj, ci + 1) * wk[(ci + 1) * 64 + lane];
                a2 += __shfl(hj, ci + 2) * wk[(ci + 2) * 64 + lane];
                a3 += __shfl(hj, ci + 3) * wk[(ci + 3) * 64 + lane];
            }
            oT[l * 65 + lane] += (a0 + a1) + (a2 + a3);
        }
    }
    __syncthreads();

    {   // SiLU + store (row index in out = parent*8 + s)
        int r = t >> 2, qq = t & 3;
        if (base + r < n) {
#pragma unroll
            for (int j = 0; j < 4; ++j) {
                float4 v = *(float4*)&oT[r * 65 + qq * 16 + j * 4];
                v.x = v.x / (1.f + __expf(-v.x));
                v.y = v.y / (1.f + __expf(-v.y));
                v.z = v.z / (1.f + __expf(-v.z));
                v.w = v.w / (1.f + __expf(-v.w));
                *(float4*)&out[((size_t)(base + r) * 8 + s) * 64 + qq * 16 + j * 4] = v;
            }
        }
    }
}

// ---------------------------------------------------------------------------
extern "C" void kernel_launch(void* const* d_in, const int* in_sizes, int n_in,
                              void* d_out, int out_size, void* d_ws,
                              size_t ws_size, hipStream_t stream) {
    const int* coords = (const int*)d_in[0];
    const float* feats = (const float*)d_in[1];
    const float* W1 = (const float*)d_in[2];
    const float* b1 = (const float*)d_in[3];
    const float* W2 = (const float*)d_in[4];
    const float* b2 = (const float*)d_in[5];
    float* out = (float*)d_out;

    int n = in_sizes[0] / 3;  // 20000

    char* ws = (char*)d_ws;
    size_t off = 0;
    auto alloc = [&](size_t bytes) {
        size_t o = off;
        off = (off + bytes + 255) & ~(size_t)255;
        return o;
    };
    int*   grid1 = (int*)(ws + alloc((size_t)GRID_VOX * 4));        // 3.54 MB
    float* h     = (float*)(ws + alloc((size_t)n * 64 * 4));        // 5.12 MB
    float* W1T13 = (float*)(ws + alloc(4096 * 4));                  // 16 KB
    float* W2Tc  = (float*)(ws + alloc(8 * 4096 * 4));              // 128 KB
    float* W2e   = (float*)(ws + alloc(64 * 4096 * 4));             // 1 MB
    int*   c1    = (int*)(ws + alloc((size_t)n * 9 * 4));           // c1[n]+c2s[8n]
    int*   c2s   = c1 + n;
    int*   p1    = (int*)(ws + alloc((size_t)n * CAP1 * 4));        // 2.56 MB
    int*   p2s   = (int*)(ws + alloc((size_t)n * 8 * CAP2S * 4));   // 5.12 MB

    hipMemsetAsync(grid1, 0xFF, (size_t)GRID_VOX * 4, stream);

    scatter_grid_kernel<<<(n + 255) / 256, 256, 0, stream>>>(coords, grid1, n);
    prep_weights_kernel<<<73 * 16, 256, 0, stream>>>(W1, W2, W1T13, W2Tc, W2e);
    build_pairs_kernel<<<(n + 255) / 256, 256, 0, stream>>>(
        coords, grid1, c1, p1, c2s, p2s, n);

    int nblk = (n + 63) / 64;
    conv1_fused_kernel<<<nblk, 256, 0, stream>>>(feats, W1, W1T13, b1, c1, p1, h, n);
    conv2_fused_kernel<<<dim3(nblk, 8), 256, 0, stream>>>(h, W2Tc, W2e, b2,
                                                          c2s, p2s, out, n);
}

// Round 6
// 186.086 us; speedup vs baseline: 3.2460x; 1.1188x over previous
//
#include <hip/hip_runtime.h>

#define D1 96
#define GRID_VOX (D1 * D1 * D1)
#define CAP1 32   // per-parent conv1 pairs (max 26 exact)
#define CAP2S 8   // per-(parent,s) conv2 pairs (max 7 exact)

// entry encoding: j (bits 0..16) | tag (bits 17..21) | row (bits 23..28, added at staging)

// ---------------------------------------------------------------------------
__global__ void scatter_grid_kernel(const int* __restrict__ coords,
                                    int* __restrict__ grid, int n) {
    int i = blockIdx.x * blockDim.x + threadIdx.x;
    if (i < n)
        grid[(coords[3 * i] * D1 + coords[3 * i + 1]) * D1 + coords[3 * i + 2]] = i;
}

// ---------------------------------------------------------------------------
// W1T13[co*64+ci] = W1[13][ci][co]                          (4096)
// W2Tc[s][co*64+ci] = sum_{self-parent taps} W2[k][ci][co]  (8*4096)
// W2e[sd][ci*64+co] = sum_{taps->sd} W2[k][ci][co]          (64*4096, orig layout)
// ---------------------------------------------------------------------------
__global__ void prep_weights_kernel(const float* __restrict__ W1,
                                    const float* __restrict__ W2,
                                    float* __restrict__ W1T13,
                                    float* __restrict__ W2Tc,
                                    float* __restrict__ W2e) {
    int t = blockIdx.x * blockDim.x + threadIdx.x;
    if (t >= 73 * 4096) return;
    if (t < 4096) {
        int co = t >> 6, ci = t & 63;
        W1T13[t] = W1[13 * 4096 + ci * 64 + co];
    } else if (t < 9 * 4096) {
        int r = t - 4096;
        int s = r >> 12, e = r & 4095;
        int co = e >> 6, ci = e & 63;
        int sa[3] = { (s >> 2) & 1, (s >> 1) & 1, s & 1 };
        float sum = 0.f;
        for (int o0 = -sa[0]; o0 <= 1 - sa[0]; ++o0)
            for (int o1 = -sa[1]; o1 <= 1 - sa[1]; ++o1)
                for (int o2 = -sa[2]; o2 <= 1 - sa[2]; ++o2) {
                    int k = (o0 + 1) * 9 + (o1 + 1) * 3 + (o2 + 1);
                    sum += W2[k * 4096 + ci * 64 + co];
                }
        W2Tc[s * 4096 + co * 64 + ci] = sum;
    } else {
        int r = t - 9 * 4096;
        int sd = r >> 12, e = r & 4095;  // e = ci*64+co
        int s = sd >> 3, d = sd & 7;
        int sa[3] = { (s >> 2) & 1, (s >> 1) & 1, s & 1 };
        int da[3] = { (d >> 2) & 1, (d >> 1) & 1, d & 1 };
        int lo[3], hi[3];
        for (int a = 0; a < 3; ++a) {
            int p = sa[a] - 1 + da[a];
            int l = 2 * p - sa[a];     if (l < -1) l = -1;
            int h = 2 * p + 1 - sa[a]; if (h > 1) h = 1;
            lo[a] = l; hi[a] = h;
        }
        float sum = 0.f;
        for (int o0 = lo[0]; o0 <= hi[0]; ++o0)
            for (int o1 = lo[1]; o1 <= hi[1]; ++o1)
                for (int o2 = lo[2]; o2 <= hi[2]; ++o2) {
                    int k = (o0 + 1) * 9 + (o1 + 1) * 3 + (o2 + 1);
                    sum += W2[k * 4096 + e];
                }
        W2e[sd * 4096 + e] = sum;
    }
}

// ---------------------------------------------------------------------------
// Per-voxel pair builder: 27 independent gathers up front (pipelined), then
// unrolled emission. conv1: j|(k<<17); conv2 bucket (i,s): j|(d<<17).
// ---------------------------------------------------------------------------
__global__ void build_pairs_kernel(const int* __restrict__ coords,
                                   const int* __restrict__ grid,
                                   int* __restrict__ c1, int* __restrict__ p1,
                                   int* __restrict__ c2s, int* __restrict__ p2s,
                                   int n) {
    int i = blockIdx.x * blockDim.x + threadIdx.x;
    if (i >= n) return;
    int c0 = coords[3 * i], cc1 = coords[3 * i + 1], cc2 = coords[3 * i + 2];

    int jv[27];
#pragma unroll
    for (int k = 0; k < 27; ++k) {
        int o0 = k / 9 - 1, o1 = (k / 3) % 3 - 1, o2 = k % 3 - 1;
        int x0 = c0 + o0, x1 = cc1 + o1, x2 = cc2 + o2;
        bool inb = (unsigned)x0 < D1 && (unsigned)x1 < D1 && (unsigned)x2 < D1;
        jv[k] = inb ? grid[(x0 * D1 + x1) * D1 + x2] : -1;
    }

    int n1 = 0;
    int n2[8] = {0, 0, 0, 0, 0, 0, 0, 0};
#pragma unroll
    for (int k = 0; k < 27; ++k) {
        if (k == 13) continue;
        int j = jv[k];
        if (j < 0) continue;
        int o0 = k / 9 - 1, o1 = (k / 3) % 3 - 1, o2 = k % 3 - 1;
        p1[(size_t)i * CAP1 + n1] = j | (k << 17);
        ++n1;
#pragma unroll
        for (int s = 0; s < 8; ++s) {
            int d0 = o0 + 1 - ((s >> 2) & 1);
            int d1 = o1 + 1 - ((s >> 1) & 1);
            int d2 = o2 + 1 - (s & 1);
            if (((d0 | d1 | d2) & ~1) == 0) {
                int d = (d0 << 2) | (d1 << 1) | d2;
                p2s[((size_t)i * 8 + s) * CAP2S + n2[s]] = j | (d << 17);
                ++n2[s];
            }
        }
    }
    c1[i] = n1;
#pragma unroll
    for (int s = 0; s < 8; ++s) c2s[i * 8 + s] = n2[s];
}

// float index of 16B chunk c4 (0..15) in row r of a swizzled 64x64 tile
__device__ __forceinline__ int swz(int r, int c4) {
    return r * 64 + ((c4 ^ (r & 15)) << 2);
}

// ---------------------------------------------------------------------------
// Fused conv kernel body (shared by conv1/conv2 via template-ish macro style):
// 256 thr = 4 waves, one 64-row tile. Phases:
//  1 stage fT (swizzled, coalesced)  2 f[16] regs  3 compact pairs into fT
//  4 dense (wave w: col-groups 4w..4w+3)  5 pair-parallel fixups (ds_add)
//  6 SiLU + coalesced store
// ---------------------------------------------------------------------------
__global__ __launch_bounds__(256) void conv1_fused_kernel(
    const float* __restrict__ feats, const float* __restrict__ W1,
    const float* __restrict__ W1T13, const float* __restrict__ b1,
    const int* __restrict__ c1, const int* __restrict__ p1,
    float* __restrict__ h, int n) {
    __shared__ __align__(16) float fT[4096];
    __shared__ __align__(16) float oT[4096];
    int* fTi = (int*)fT;
    int base = blockIdx.x * 64;
    int t = threadIdx.x, w = t >> 6, lane = t & 63;

    {   // 1. stage
        int r = t >> 2, q0 = (t & 3) * 4;
        bool v = (base + r) < n;
        const float4* src = (const float4*)(feats + (size_t)(base + r) * 64 + q0 * 4);
        float4 z = make_float4(0.f, 0.f, 0.f, 0.f);
#pragma unroll
        for (int j = 0; j < 4; ++j)
            *(float4*)&fT[swz(r, q0 + j)] = v ? src[j] : z;
    }
    __syncthreads();

    float4 f[16];  // 2. row features in registers
#pragma unroll
    for (int q = 0; q < 16; ++q) f[q] = *(float4*)&fT[swz(lane, q)];
    __syncthreads();  // fT free

    if (t == 0) fTi[0] = 0;
    __syncthreads();

    // 3. compact pairs (threads 0..63, one row each)
    if (t < 64) {
        int row = base + t;
        int cnt = (row < n) ? c1[row] : 0;
        if (cnt > 0) {
            int off = atomicAdd(fTi, cnt);
            for (int e2 = 0; e2 < cnt; ++e2)
                fTi[1 + off + e2] = p1[(size_t)row * CAP1 + e2] | (t << 23);
        }
    }

    // 4. dense (no barrier needed: disjoint LDS regions)
    const float4* wbase = (const float4*)W1T13;
    const float4* b4 = (const float4*)b1;
#pragma unroll 1
    for (int c = 0; c < 4; ++c) {
        int cg = w * 4 + c;
        float4 acc = b4[cg];
        const float4* w4 = wbase + (size_t)cg * 64;
#pragma unroll
        for (int q = 0; q < 16; ++q) {
            float4 fq = f[q];
            float4 wa = w4[q], wb = w4[16 + q], wc = w4[32 + q], wd = w4[48 + q];
            acc.x += fq.x * wa.x + fq.y * wa.y + fq.z * wa.z + fq.w * wa.w;
            acc.y += fq.x * wb.x + fq.y * wb.y + fq.z * wb.z + fq.w * wb.w;
            acc.z += fq.x * wc.x + fq.y * wc.y + fq.z * wc.z + fq.w * wc.w;
            acc.w += fq.x * wd.x + fq.y * wd.y + fq.z * wd.z + fq.w * wd.w;
        }
        *(float4*)&oT[swz(lane, cg)] = acc;
    }
    __syncthreads();

    // 5. pair-parallel fixups
    int np = fTi[0];
    for (int p = w; p < np; p += 4) {
        int se = __builtin_amdgcn_readfirstlane(fTi[1 + p]);
        int j = se & 0x1FFFF, tag = (se >> 17) & 31, l = (se >> 23) & 63;
        const float* fj = feats + (size_t)j * 64;   // uniform -> scalar loads
        const float* wk = W1 + (size_t)tag * 4096;  // [ci][co]
        float a0 = 0.f, a1 = 0.f, a2 = 0.f, a3 = 0.f;
#pragma unroll
        for (int c4 = 0; c4 < 16; ++c4) {
            float4 fv = *(const float4*)(fj + c4 * 4);
            a0 += fv.x * wk[(c4 * 4 + 0) * 64 + lane];
            a1 += fv.y * wk[(c4 * 4 + 1) * 64 + lane];
            a2 += fv.z * wk[(c4 * 4 + 2) * 64 + lane];
            a3 += fv.w * wk[(c4 * 4 + 3) * 64 + lane];
        }
        int fi = l * 64 + (((((lane >> 2)) ^ (l & 15)) << 2) | (lane & 3));
        atomicAdd(&oT[fi], (a0 + a1) + (a2 + a3));
    }
    __syncthreads();

    {   // 6. SiLU + store
        int r = t >> 2, q0 = (t & 3) * 4;
        if (base + r < n) {
#pragma unroll
            for (int j = 0; j < 4; ++j) {
                float4 v = *(float4*)&oT[swz(r, q0 + j)];
                v.x = v.x / (1.f + __expf(-v.x));
                v.y = v.y / (1.f + __expf(-v.y));
                v.z = v.z / (1.f + __expf(-v.z));
                v.w = v.w / (1.f + __expf(-v.w));
                *(float4*)&h[(size_t)(base + r) * 64 + q0 * 4 + j * 4] = v;
            }
        }
    }
}

// ---------------------------------------------------------------------------
__global__ __launch_bounds__(256) void conv2_fused_kernel(
    const float* __restrict__ h, const float* __restrict__ W2Tc,
    const float* __restrict__ W2e, const float* __restrict__ b2,
    const int* __restrict__ c2s, const int* __restrict__ p2s,
    float* __restrict__ out, int n) {
    __shared__ __align__(16) float fT[4096];
    __shared__ __align__(16) float oT[4096];
    int* fTi = (int*)fT;
    int base = blockIdx.x * 64;
    int s = blockIdx.y;
    int t = threadIdx.x, w = t >> 6, lane = t & 63;

    {   // 1. stage
        int r = t >> 2, q0 = (t & 3) * 4;
        bool v = (base + r) < n;
        const float4* src = (const float4*)(h + (size_t)(base + r) * 64 + q0 * 4);
        float4 z = make_float4(0.f, 0.f, 0.f, 0.f);
#pragma unroll
        for (int j = 0; j < 4; ++j)
            *(float4*)&fT[swz(r, q0 + j)] = v ? src[j] : z;
    }
    __syncthreads();

    float4 f[16];
#pragma unroll
    for (int q = 0; q < 16; ++q) f[q] = *(float4*)&fT[swz(lane, q)];
    __syncthreads();

    if (t == 0) fTi[0] = 0;
    __syncthreads();

    if (t < 64) {
        int row = base + t;
        int cnt = (row < n) ? c2s[(size_t)row * 8 + s] : 0;
        if (cnt > 0) {
            int off = atomicAdd(fTi, cnt);
            for (int e2 = 0; e2 < cnt; ++e2)
                fTi[1 + off + e2] = p2s[((size_t)row * 8 + s) * CAP2S + e2] | (t << 23);
        }
    }

    const float4* wbase = (const float4*)(W2Tc + (size_t)s * 4096);
    const float4* b4 = (const float4*)b2;
#pragma unroll 1
    for (int c = 0; c < 4; ++c) {
        int cg = w * 4 + c;
        float4 acc = b4[cg];
        const float4* w4 = wbase + (size_t)cg * 64;
#pragma unroll
        for (int q = 0; q < 16; ++q) {
            float4 fq = f[q];
            float4 wa = w4[q], wb = w4[16 + q], wc = w4[32 + q], wd = w4[48 + q];
            acc.x += fq.x * wa.x + fq.y * wa.y + fq.z * wa.z + fq.w * wa.w;
            acc.y += fq.x * wb.x + fq.y * wb.y + fq.z * wb.z + fq.w * wb.w;
            acc.z += fq.x * wc.x + fq.y * wc.y + fq.z * wc.z + fq.w * wc.w;
            acc.w += fq.x * wd.x + fq.y * wd.y + fq.z * wd.z + fq.w * wd.w;
        }
        *(float4*)&oT[swz(lane, cg)] = acc;
    }
    __syncthreads();

    int np = fTi[0];
    for (int p = w; p < np; p += 4) {
        int se = __builtin_amdgcn_readfirstlane(fTi[1 + p]);
        int j = se & 0x1FFFF, d = (se >> 17) & 31, l = (se >> 23) & 63;
        const float* fj = h + (size_t)j * 64;
        const float* wk = W2e + (size_t)(s * 8 + d) * 4096;  // [ci][co]
        float a0 = 0.f, a1 = 0.f, a2 = 0.f, a3 = 0.f;
#pragma unroll
        for (int c4 = 0; c4 < 16; ++c4) {
            float4 fv = *(const float4*)(fj + c4 * 4);
            a0 += fv.x * wk[(c4 * 4 + 0) * 64 + lane];
            a1 += fv.y * wk[(c4 * 4 + 1) * 64 + lane];
            a2 += fv.z * wk[(c4 * 4 + 2) * 64 + lane];
            a3 += fv.w * wk[(c4 * 4 + 3) * 64 + lane];
        }
        int fi = l * 64 + (((((lane >> 2)) ^ (l & 15)) << 2) | (lane & 3));
        atomicAdd(&oT[fi], (a0 + a1) + (a2 + a3));
    }
    __syncthreads();

    {   // SiLU + store (out row = parent*8 + s)
        int r = t >> 2, q0 = (t & 3) * 4;
        if (base + r < n) {
#pragma unroll
            for (int j = 0; j < 4; ++j) {
                float4 v = *(float4*)&oT[swz(r, q0 + j)];
                v.x = v.x / (1.f + __expf(-v.x));
                v.y = v.y / (1.f + __expf(-v.y));
                v.z = v.z / (1.f + __expf(-v.z));
                v.w = v.w / (1.f + __expf(-v.w));
                *(float4*)&out[((size_t)(base + r) * 8 + s) * 64 + q0 * 4 + j * 4] = v;
            }
        }
    }
}

// ---------------------------------------------------------------------------
extern "C" void kernel_launch(void* const* d_in, const int* in_sizes, int n_in,
                              void* d_out, int out_size, void* d_ws,
                              size_t ws_size, hipStream_t stream) {
    const int* coords = (const int*)d_in[0];
    const float* feats = (const float*)d_in[1];
    const float* W1 = (const float*)d_in[2];
    const float* b1 = (const float*)d_in[3];
    const float* W2 = (const float*)d_in[4];
    const float* b2 = (const float*)d_in[5];
    float* out = (float*)d_out;

    int n = in_sizes[0] / 3;  // 20000

    char* ws = (char*)d_ws;
    size_t off = 0;
    auto alloc = [&](size_t bytes) {
        size_t o = off;
        off = (off + bytes + 255) & ~(size_t)255;
        return o;
    };
    int*   grid1 = (int*)(ws + alloc((size_t)GRID_VOX * 4));        // 3.54 MB
    float* h     = (float*)(ws + alloc((size_t)n * 64 * 4));        // 5.12 MB
    float* W1T13 = (float*)(ws + alloc(4096 * 4));                  // 16 KB
    float* W2Tc  = (float*)(ws + alloc(8 * 4096 * 4));              // 128 KB
    float* W2e   = (float*)(ws + alloc(64 * 4096 * 4));             // 1 MB
    int*   c1    = (int*)(ws + alloc((size_t)n * 9 * 4));           // c1[n]+c2s[8n]
    int*   c2s   = c1 + n;
    int*   p1    = (int*)(ws + alloc((size_t)n * CAP1 * 4));        // 2.56 MB
    int*   p2s   = (int*)(ws + alloc((size_t)n * 8 * CAP2S * 4));   // 5.12 MB

    hipMemsetAsync(grid1, 0xFF, (size_t)GRID_VOX * 4, stream);

    scatter_grid_kernel<<<(n + 255) / 256, 256, 0, stream>>>(coords, grid1, n);
    prep_weights_kernel<<<73 * 16, 256, 0, stream>>>(W1, W2, W1T13, W2Tc, W2e);
    build_pairs_kernel<<<(n + 255) / 256, 256, 0, stream>>>(
        coords, grid1, c1, p1, c2s, p2s, n);

    int nblk = (n + 63) / 64;
    conv1_fused_kernel<<<nblk, 256, 0, stream>>>(feats, W1, W1T13, b1, c1, p1, h, n);
    conv2_fused_kernel<<<dim3(nblk, 8), 256, 0, stream>>>(h, W2Tc, W2e, b2,
                                                          c2s, p2s, out, n);
}

// Round 7
// 90.289 us; speedup vs baseline: 6.6901x; 2.0610x over previous
//
#include <hip/hip_runtime.h>

#define D1 96
#define GRID_VOX (D1 * D1 * D1)
#define CAP1 32   // per-parent conv1 pairs (max 26 exact)
#define CAP2S 8   // per-(parent,s) conv2 pairs (max 7 exact)

typedef __attribute__((ext_vector_type(8))) short short8_t;  // 8 bf16
typedef __attribute__((ext_vector_type(4))) float f32x4;

__device__ __forceinline__ unsigned short bf16rne(float x) {
    unsigned u = __float_as_uint(x);
    return (unsigned short)((u + 0x7FFF + ((u >> 16) & 1)) >> 16);
}
__device__ __forceinline__ void split2(float v, unsigned short& hi,
                                       unsigned short& lo) {
    hi = bf16rne(v);
    float hf = __uint_as_float((unsigned)hi << 16);
    lo = bf16rne(v - hf);
}

// ---------------------------------------------------------------------------
__global__ void scatter_grid_kernel(const int* __restrict__ coords,
                                    unsigned short* __restrict__ grid, int n) {
    int i = blockIdx.x * blockDim.x + threadIdx.x;
    if (i < n)
        grid[(coords[3 * i] * D1 + coords[3 * i + 1]) * D1 + coords[3 * i + 2]] =
            (unsigned short)(i + 1);
}

// ---------------------------------------------------------------------------
// Packs MFMA B-fragments (bf16 hi/lo) + fp32 fixup weights.
// conv1 dense: W1[13] (self tap).    fid1 = kb*4+c, elem e:
//   ci = kb*32+(l>>4)*8+e, co = c*16+(l&15)
// conv2 dense: fold of parent-offset-0 taps per child s. fid2 = (s*2+kb)*4+c.
// W2e[sd][ci*64+co] = fold of taps -> (s,d) for fixups (fp32).
// ---------------------------------------------------------------------------
__global__ void prep_weights_kernel(const float* __restrict__ W1,
                                    const float* __restrict__ W2,
                                    unsigned short* __restrict__ Wpk1h,
                                    unsigned short* __restrict__ Wpk1l,
                                    unsigned short* __restrict__ Wpk2h,
                                    unsigned short* __restrict__ Wpk2l,
                                    float* __restrict__ W2e) {
    int t = blockIdx.x * blockDim.x + threadIdx.x;
    if (t < 512) {  // conv1 fragments
        int fid = t >> 6, l = t & 63;
        int kb = fid >> 2, c = fid & 3;
#pragma unroll
        for (int e = 0; e < 8; ++e) {
            int ci = kb * 32 + ((l >> 4) << 3) + e;
            int co = c * 16 + (l & 15);
            unsigned short hi, lo;
            split2(W1[13 * 4096 + ci * 64 + co], hi, lo);
            Wpk1h[(size_t)t * 8 + e] = hi;
            Wpk1l[(size_t)t * 8 + e] = lo;
        }
    } else if (t < 512 + 4096) {  // conv2 dense (self-parent fold) fragments
        int u = t - 512;
        int fid = u >> 6, l = u & 63;
        int s = fid >> 3, kb = (fid >> 2) & 1, c = fid & 3;
        int s0 = (s >> 2) & 1, s1 = (s >> 1) & 1, s2 = s & 1;
#pragma unroll
        for (int e = 0; e < 8; ++e) {
            int ci = kb * 32 + ((l >> 4) << 3) + e;
            int co = c * 16 + (l & 15);
            float sum = 0.f;
            for (int o0 = -s0; o0 <= 1 - s0; ++o0)
                for (int o1 = -s1; o1 <= 1 - s1; ++o1)
                    for (int o2 = -s2; o2 <= 1 - s2; ++o2) {
                        int k = (o0 + 1) * 9 + (o1 + 1) * 3 + (o2 + 1);
                        sum += W2[k * 4096 + ci * 64 + co];
                    }
            unsigned short hi, lo;
            split2(sum, hi, lo);
            Wpk2h[(size_t)u * 8 + e] = hi;
            Wpk2l[(size_t)u * 8 + e] = lo;
        }
    } else {  // W2e fp32 for fixups
        int r = t - 4608;
        if (r >= 64 * 4096) return;
        int sd = r >> 12, e = r & 4095;
        int s = sd >> 3, d = sd & 7;
        int sa[3] = { (s >> 2) & 1, (s >> 1) & 1, s & 1 };
        int da[3] = { (d >> 2) & 1, (d >> 1) & 1, d & 1 };
        int lo_[3], hi_[3];
        for (int a = 0; a < 3; ++a) {
            int p = sa[a] - 1 + da[a];
            int l = 2 * p - sa[a];     if (l < -1) l = -1;
            int h = 2 * p + 1 - sa[a]; if (h > 1) h = 1;
            lo_[a] = l; hi_[a] = h;
        }
        float sum = 0.f;
        for (int o0 = lo_[0]; o0 <= hi_[0]; ++o0)
            for (int o1 = lo_[1]; o1 <= hi_[1]; ++o1)
                for (int o2 = lo_[2]; o2 <= hi_[2]; ++o2) {
                    int k = (o0 + 1) * 9 + (o1 + 1) * 3 + (o2 + 1);
                    sum += W2[k * 4096 + e];
                }
        W2e[(size_t)sd * 4096 + e] = sum;
    }
}

// ---------------------------------------------------------------------------
// Per-voxel pair builder (no atomics). conv1: j|(k<<17); conv2: j|(d<<17).
// ---------------------------------------------------------------------------
__global__ void build_pairs_kernel(const int* __restrict__ coords,
                                   const unsigned short* __restrict__ grid,
                                   int* __restrict__ c1, int* __restrict__ p1,
                                   int* __restrict__ c2s, int* __restrict__ p2s,
                                   int n) {
    int i = blockIdx.x * blockDim.x + threadIdx.x;
    if (i >= n) return;
    int c0 = coords[3 * i], cc1 = coords[3 * i + 1], cc2 = coords[3 * i + 2];

    int jv[27];
#pragma unroll
    for (int k = 0; k < 27; ++k) {
        int o0 = k / 9 - 1, o1 = (k / 3) % 3 - 1, o2 = k % 3 - 1;
        int x0 = c0 + o0, x1 = cc1 + o1, x2 = cc2 + o2;
        bool inb = (unsigned)x0 < D1 && (unsigned)x1 < D1 && (unsigned)x2 < D1;
        jv[k] = inb ? (int)grid[(x0 * D1 + x1) * D1 + x2] - 1 : -1;
    }

    int n1 = 0;
    int n2[8] = {0, 0, 0, 0, 0, 0, 0, 0};
#pragma unroll
    for (int k = 0; k < 27; ++k) {
        if (k == 13) continue;
        int j = jv[k];
        if (j < 0) continue;
        int o0 = k / 9 - 1, o1 = (k / 3) % 3 - 1, o2 = k % 3 - 1;
        p1[(size_t)i * CAP1 + n1] = j | (k << 17);
        ++n1;
#pragma unroll
        for (int s = 0; s < 8; ++s) {
            int d0 = o0 + 1 - ((s >> 2) & 1);
            int d1 = o1 + 1 - ((s >> 1) & 1);
            int d2 = o2 + 1 - (s & 1);
            if (((d0 | d1 | d2) & ~1) == 0) {
                int d = (d0 << 2) | (d1 << 1) | d2;
                p2s[((size_t)i * 8 + s) * CAP2S + n2[s]] = j | (d << 17);
                ++n2[s];
            }
        }
    }
    c1[i] = n1;
#pragma unroll
    for (int s = 0; s < 8; ++s) c2s[i * 8 + s] = n2[s];
}

// ---------------------------------------------------------------------------
// Shared dense helper: wave w computes rows [16w,16w+16) x all 64 cols of the
// 64x64 tile via 24 MFMAs (hi/lo split), bias added, result -> oT (linear).
// A loaded straight from global rows (rowptr = src + row*64).
// ---------------------------------------------------------------------------
__device__ __forceinline__ void dense_mfma(const float* __restrict__ src,
                                           int arow,  // global row to load
                                           const short8_t* __restrict__ Bh,
                                           const short8_t* __restrict__ Bl,
                                           const float* __restrict__ bias,
                                           float* __restrict__ oT, int w,
                                           int lane) {
    const float* ap = src + (size_t)arow * 64 + ((lane >> 4) << 3);
    f32x4 a0 = *(const f32x4*)(ap);
    f32x4 a1 = *(const f32x4*)(ap + 4);
    f32x4 a2 = *(const f32x4*)(ap + 32);
    f32x4 a3 = *(const f32x4*)(ap + 36);

    short8_t ah0, al0, ah1, al1;
#pragma unroll
    for (int e = 0; e < 4; ++e) {
        unsigned short hh, ll;
        split2(a0[e], hh, ll); ah0[e] = (short)hh; al0[e] = (short)ll;
        split2(a1[e], hh, ll); ah0[4 + e] = (short)hh; al0[4 + e] = (short)ll;
        split2(a2[e], hh, ll); ah1[e] = (short)hh; al1[e] = (short)ll;
        split2(a3[e], hh, ll); ah1[4 + e] = (short)hh; al1[4 + e] = (short)ll;
    }

#pragma unroll 1
    for (int c = 0; c < 4; ++c) {
        short8_t bh0 = Bh[c * 64 + lane];
        short8_t bl0 = Bl[c * 64 + lane];
        short8_t bh1 = Bh[(4 + c) * 64 + lane];
        short8_t bl1 = Bl[(4 + c) * 64 + lane];
        f32x4 acc = {0.f, 0.f, 0.f, 0.f};
        acc = __builtin_amdgcn_mfma_f32_16x16x32_bf16(ah0, bh0, acc, 0, 0, 0);
        acc = __builtin_amdgcn_mfma_f32_16x16x32_bf16(al0, bh0, acc, 0, 0, 0);
        acc = __builtin_amdgcn_mfma_f32_16x16x32_bf16(ah0, bl0, acc, 0, 0, 0);
        acc = __builtin_amdgcn_mfma_f32_16x16x32_bf16(ah1, bh1, acc, 0, 0, 0);
        acc = __builtin_amdgcn_mfma_f32_16x16x32_bf16(al1, bh1, acc, 0, 0, 0);
        acc = __builtin_amdgcn_mfma_f32_16x16x32_bf16(ah1, bl1, acc, 0, 0, 0);
        int col = c * 16 + (lane & 15);
        float bb = bias[col];
#pragma unroll
        for (int r = 0; r < 4; ++r) {
            int row = w * 16 + ((lane >> 4) << 2) + r;
            oT[row * 64 + col] = acc[r] + bb;
        }
    }
}

// fixup: one pair, lane = out channel; fj uniform (scalar), wk coalesced vector
__device__ __forceinline__ void fixup_pair(const float* __restrict__ fj,
                                           const float* __restrict__ wk,
                                           float* __restrict__ oT, int l,
                                           int lane) {
    float a0 = 0.f, a1 = 0.f, a2 = 0.f, a3 = 0.f;
#pragma unroll
    for (int c4 = 0; c4 < 16; ++c4) {
        f32x4 fv = *(const f32x4*)(fj + c4 * 4);
        a0 += fv[0] * wk[(c4 * 4 + 0) * 64 + lane];
        a1 += fv[1] * wk[(c4 * 4 + 1) * 64 + lane];
        a2 += fv[2] * wk[(c4 * 4 + 2) * 64 + lane];
        a3 += fv[3] * wk[(c4 * 4 + 3) * 64 + lane];
    }
    atomicAdd(&oT[l * 64 + lane], (a0 + a1) + (a2 + a3));
}

// ---------------------------------------------------------------------------
__global__ __launch_bounds__(256) void conv1_fused_kernel(
    const float* __restrict__ feats, const float* __restrict__ W1,
    const unsigned short* __restrict__ Wpk1h,
    const unsigned short* __restrict__ Wpk1l, const float* __restrict__ b1,
    const int* __restrict__ c1, const int* __restrict__ p1,
    float* __restrict__ h, int n) {
    __shared__ __align__(16) float oT[4096];
    __shared__ int pl[1 + 64 * 26];
    int base = blockIdx.x * 64;
    int t = threadIdx.x, w = t >> 6, lane = t & 63;

    if (t == 0) pl[0] = 0;
    __syncthreads();
    if (t < 64) {  // compact pairs
        int row = base + t;
        int cnt = (row < n) ? c1[row] : 0;
        if (cnt > 0) {
            int off = atomicAdd(pl, cnt);
            for (int e = 0; e < cnt; ++e)
                pl[1 + off + e] = p1[(size_t)row * CAP1 + e] | (t << 23);
        }
    }

    int arow = base + w * 16 + (lane & 15);
    if (arow >= n) arow = n - 1;
    dense_mfma(feats, arow, (const short8_t*)Wpk1h, (const short8_t*)Wpk1l,
               b1, oT, w, lane);
    __syncthreads();

    int np = pl[0];
    for (int p = w; p < np; p += 4) {
        int se = pl[1 + p];
        se = __builtin_amdgcn_readfirstlane(se);
        int j = se & 0x1FFFF, k = (se >> 17) & 31, l = (se >> 23) & 63;
        fixup_pair(feats + (size_t)j * 64, W1 + (size_t)k * 4096, oT, l, lane);
    }
    __syncthreads();

    {  // SiLU + coalesced store
        int r = t >> 2, q0 = (t & 3) * 16;
        if (base + r < n) {
#pragma unroll
            for (int jj = 0; jj < 4; ++jj) {
                f32x4 v = *(f32x4*)&oT[r * 64 + q0 + jj * 4];
#pragma unroll
                for (int u = 0; u < 4; ++u) v[u] = v[u] / (1.f + __expf(-v[u]));
                *(f32x4*)&h[(size_t)(base + r) * 64 + q0 + jj * 4] = v;
            }
        }
    }
}

// ---------------------------------------------------------------------------
__global__ __launch_bounds__(256) void conv2_fused_kernel(
    const float* __restrict__ h, const unsigned short* __restrict__ Wpk2h,
    const unsigned short* __restrict__ Wpk2l, const float* __restrict__ W2e,
    const float* __restrict__ b2, const int* __restrict__ c2s,
    const int* __restrict__ p2s, float* __restrict__ out, int n) {
    __shared__ __align__(16) float oT[4096];
    __shared__ int pl[1 + 64 * 7];
    int base = blockIdx.x * 64, s = blockIdx.y;
    int t = threadIdx.x, w = t >> 6, lane = t & 63;

    if (t == 0) pl[0] = 0;
    __syncthreads();
    if (t < 64) {
        int row = base + t;
        int cnt = (row < n) ? c2s[(size_t)row * 8 + s] : 0;
        if (cnt > 0) {
            int off = atomicAdd(pl, cnt);
            for (int e = 0; e < cnt; ++e)
                pl[1 + off + e] = p2s[((size_t)row * 8 + s) * CAP2S + e] | (t << 23);
        }
    }

    int arow = base + w * 16 + (lane & 15);
    if (arow >= n) arow = n - 1;
    dense_mfma(h, arow, (const short8_t*)Wpk2h + (size_t)s * 8 * 64,
               (const short8_t*)Wpk2l + (size_t)s * 8 * 64, b2, oT, w, lane);
    __syncthreads();

    int np = pl[0];
    for (int p = w; p < np; p += 4) {
        int se = pl[1 + p];
        se = __builtin_amdgcn_readfirstlane(se);
        int j = se & 0x1FFFF, d = (se >> 17) & 31, l = (se >> 23) & 63;
        fixup_pair(h + (size_t)j * 64, W2e + (size_t)(s * 8 + d) * 4096, oT, l,
                   lane);
    }
    __syncthreads();

    {  // SiLU + store (out row = parent*8 + s)
        int r = t >> 2, q0 = (t & 3) * 16;
        if (base + r < n) {
#pragma unroll
            for (int jj = 0; jj < 4; ++jj) {
                f32x4 v = *(f32x4*)&oT[r * 64 + q0 + jj * 4];
#pragma unroll
                for (int u = 0; u < 4; ++u) v[u] = v[u] / (1.f + __expf(-v[u]));
                *(f32x4*)&out[((size_t)(base + r) * 8 + s) * 64 + q0 + jj * 4] = v;
            }
        }
    }
}

// ---------------------------------------------------------------------------
extern "C" void kernel_launch(void* const* d_in, const int* in_sizes, int n_in,
                              void* d_out, int out_size, void* d_ws,
                              size_t ws_size, hipStream_t stream) {
    const int* coords = (const int*)d_in[0];
    const float* feats = (const float*)d_in[1];
    const float* W1 = (const float*)d_in[2];
    const float* b1 = (const float*)d_in[3];
    const float* W2 = (const float*)d_in[4];
    const float* b2 = (const float*)d_in[5];
    float* out = (float*)d_out;

    int n = in_sizes[0] / 3;  // 20000

    char* ws = (char*)d_ws;
    size_t off = 0;
    auto alloc = [&](size_t bytes) {
        size_t o = off;
        off = (off + bytes + 255) & ~(size_t)255;
        return o;
    };
    unsigned short* grid1 = (unsigned short*)(ws + alloc((size_t)GRID_VOX * 2));
    float* h      = (float*)(ws + alloc((size_t)n * 64 * 4));     // 5.12 MB
    float* W2e    = (float*)(ws + alloc(64 * 4096 * 4));          // 1 MB
    unsigned short* Wpk1h = (unsigned short*)(ws + alloc(512 * 8 * 2));
    unsigned short* Wpk1l = (unsigned short*)(ws + alloc(512 * 8 * 2));
    unsigned short* Wpk2h = (unsigned short*)(ws + alloc(4096 * 8 * 2));
    unsigned short* Wpk2l = (unsigned short*)(ws + alloc(4096 * 8 * 2));
    int*   c1     = (int*)(ws + alloc((size_t)n * 9 * 4));        // c1[n]+c2s[8n]
    int*   c2s    = c1 + n;
    int*   p1     = (int*)(ws + alloc((size_t)n * CAP1 * 4));     // 2.56 MB
    int*   p2s    = (int*)(ws + alloc((size_t)n * 8 * CAP2S * 4)); // 5.12 MB

    hipMemsetAsync(grid1, 0, (size_t)GRID_VOX * 2, stream);

    scatter_grid_kernel<<<(n + 255) / 256, 256, 0, stream>>>(coords, grid1, n);
    prep_weights_kernel<<<(4608 + 64 * 4096 + 255) / 256, 256, 0, stream>>>(
        W1, W2, Wpk1h, Wpk1l, Wpk2h, Wpk2l, W2e);
    build_pairs_kernel<<<(n + 255) / 256, 256, 0, stream>>>(
        coords, grid1, c1, p1, c2s, p2s, n);

    int nblk = (n + 63) / 64;
    conv1_fused_kernel<<<nblk, 256, 0, stream>>>(feats, W1, Wpk1h, Wpk1l, b1,
                                                 c1, p1, h, n);
    conv2_fused_kernel<<<dim3(nblk, 8), 256, 0, stream>>>(
        h, Wpk2h, Wpk2l, W2e, b2, c2s, p2s, out, n);
}

// Round 8
// 90.182 us; speedup vs baseline: 6.6980x; 1.0012x over previous
//
#include <hip/hip_runtime.h>

#define D1 96
#define GRID_VOX (D1 * D1 * D1)
#define CAP1 32   // per-parent conv1 pairs (max 26 exact)
#define CAP2S 8   // per-(parent,s) conv2 pairs (max 7 exact)

typedef __attribute__((ext_vector_type(8))) short short8_t;  // 8 bf16
typedef __attribute__((ext_vector_type(4))) float f32x4;

__device__ __forceinline__ unsigned short bf16rne(float x) {
    unsigned u = __float_as_uint(x);
    return (unsigned short)((u + 0x7FFF + ((u >> 16) & 1)) >> 16);
}
__device__ __forceinline__ void split2(float v, unsigned short& hi,
                                       unsigned short& lo) {
    hi = bf16rne(v);
    float hf = __uint_as_float((unsigned)hi << 16);
    lo = bf16rne(v - hf);
}

// ---------------------------------------------------------------------------
// Fast zero-fill for the lookup grid (int4 grid-stride; ~0.9 µs at BW)
// ---------------------------------------------------------------------------
__global__ void fill_grid_kernel(int4* __restrict__ p, int n16) {
    int t = blockIdx.x * blockDim.x + threadIdx.x;
    int4 z = make_int4(0, 0, 0, 0);
    for (; t < n16; t += gridDim.x * blockDim.x) p[t] = z;
}

// ---------------------------------------------------------------------------
__global__ void scatter_grid_kernel(const int* __restrict__ coords,
                                    unsigned short* __restrict__ grid, int n) {
    int i = blockIdx.x * blockDim.x + threadIdx.x;
    if (i < n)
        grid[(coords[3 * i] * D1 + coords[3 * i + 1]) * D1 + coords[3 * i + 2]] =
            (unsigned short)(i + 1);
}

// ---------------------------------------------------------------------------
// Packs MFMA B-fragments (bf16 hi/lo) + fp32 fixup weights.
// conv1 dense: W1[13] (self tap).    fid1 = kb*4+c, elem e:
//   ci = kb*32+(l>>4)*8+e, co = c*16+(l&15)
// conv2 dense: fold of parent-offset-0 taps per child s. fid2 = (s*2+kb)*4+c.
// W2e[sd][ci*64+co] = fold of taps -> (s,d) for fixups (fp32).
// ---------------------------------------------------------------------------
__global__ void prep_weights_kernel(const float* __restrict__ W1,
                                    const float* __restrict__ W2,
                                    unsigned short* __restrict__ Wpk1h,
                                    unsigned short* __restrict__ Wpk1l,
                                    unsigned short* __restrict__ Wpk2h,
                                    unsigned short* __restrict__ Wpk2l,
                                    float* __restrict__ W2e) {
    int t = blockIdx.x * blockDim.x + threadIdx.x;
    if (t < 512) {  // conv1 fragments
        int fid = t >> 6, l = t & 63;
        int kb = fid >> 2, c = fid & 3;
#pragma unroll
        for (int e = 0; e < 8; ++e) {
            int ci = kb * 32 + ((l >> 4) << 3) + e;
            int co = c * 16 + (l & 15);
            unsigned short hi, lo;
            split2(W1[13 * 4096 + ci * 64 + co], hi, lo);
            Wpk1h[(size_t)t * 8 + e] = hi;
            Wpk1l[(size_t)t * 8 + e] = lo;
        }
    } else if (t < 512 + 4096) {  // conv2 dense (self-parent fold) fragments
        int u = t - 512;
        int fid = u >> 6, l = u & 63;
        int s = fid >> 3, kb = (fid >> 2) & 1, c = fid & 3;
        int s0 = (s >> 2) & 1, s1 = (s >> 1) & 1, s2 = s & 1;
#pragma unroll
        for (int e = 0; e < 8; ++e) {
            int ci = kb * 32 + ((l >> 4) << 3) + e;
            int co = c * 16 + (l & 15);
            float sum = 0.f;
            for (int o0 = -s0; o0 <= 1 - s0; ++o0)
                for (int o1 = -s1; o1 <= 1 - s1; ++o1)
                    for (int o2 = -s2; o2 <= 1 - s2; ++o2) {
                        int k = (o0 + 1) * 9 + (o1 + 1) * 3 + (o2 + 1);
                        sum += W2[k * 4096 + ci * 64 + co];
                    }
            unsigned short hi, lo;
            split2(sum, hi, lo);
            Wpk2h[(size_t)u * 8 + e] = hi;
            Wpk2l[(size_t)u * 8 + e] = lo;
        }
    } else {  // W2e fp32 for fixups
        int r = t - 4608;
        if (r >= 64 * 4096) return;
        int sd = r >> 12, e = r & 4095;
        int s = sd >> 3, d = sd & 7;
        int sa[3] = { (s >> 2) & 1, (s >> 1) & 1, s & 1 };
        int da[3] = { (d >> 2) & 1, (d >> 1) & 1, d & 1 };
        int lo_[3], hi_[3];
        for (int a = 0; a < 3; ++a) {
            int p = sa[a] - 1 + da[a];
            int l = 2 * p - sa[a];     if (l < -1) l = -1;
            int h = 2 * p + 1 - sa[a]; if (h > 1) h = 1;
            lo_[a] = l; hi_[a] = h;
        }
        float sum = 0.f;
        for (int o0 = lo_[0]; o0 <= hi_[0]; ++o0)
            for (int o1 = lo_[1]; o1 <= hi_[1]; ++o1)
                for (int o2 = lo_[2]; o2 <= hi_[2]; ++o2) {
                    int k = (o0 + 1) * 9 + (o1 + 1) * 3 + (o2 + 1);
                    sum += W2[k * 4096 + e];
                }
        W2e[(size_t)sd * 4096 + e] = sum;
    }
}

// ---------------------------------------------------------------------------
// Per-voxel pair builder (no atomics). conv1: j|(k<<17); conv2: j|(d<<17).
// ---------------------------------------------------------------------------
__global__ void build_pairs_kernel(const int* __restrict__ coords,
                                   const unsigned short* __restrict__ grid,
                                   int* __restrict__ c1, int* __restrict__ p1,
                                   int* __restrict__ c2s, int* __restrict__ p2s,
                                   int n) {
    int i = blockIdx.x * blockDim.x + threadIdx.x;
    if (i >= n) return;
    int c0 = coords[3 * i], cc1 = coords[3 * i + 1], cc2 = coords[3 * i + 2];

    int jv[27];
#pragma unroll
    for (int k = 0; k < 27; ++k) {
        int o0 = k / 9 - 1, o1 = (k / 3) % 3 - 1, o2 = k % 3 - 1;
        int x0 = c0 + o0, x1 = cc1 + o1, x2 = cc2 + o2;
        bool inb = (unsigned)x0 < D1 && (unsigned)x1 < D1 && (unsigned)x2 < D1;
        jv[k] = inb ? (int)grid[(x0 * D1 + x1) * D1 + x2] - 1 : -1;
    }

    int n1 = 0;
    int n2[8] = {0, 0, 0, 0, 0, 0, 0, 0};
#pragma unroll
    for (int k = 0; k < 27; ++k) {
        if (k == 13) continue;
        int j = jv[k];
        if (j < 0) continue;
        int o0 = k / 9 - 1, o1 = (k / 3) % 3 - 1, o2 = k % 3 - 1;
        p1[(size_t)i * CAP1 + n1] = j | (k << 17);
        ++n1;
#pragma unroll
        for (int s = 0; s < 8; ++s) {
            int d0 = o0 + 1 - ((s >> 2) & 1);
            int d1 = o1 + 1 - ((s >> 1) & 1);
            int d2 = o2 + 1 - (s & 1);
            if (((d0 | d1 | d2) & ~1) == 0) {
                int d = (d0 << 2) | (d1 << 1) | d2;
                p2s[((size_t)i * 8 + s) * CAP2S + n2[s]] = j | (d << 17);
                ++n2[s];
            }
        }
    }
    c1[i] = n1;
#pragma unroll
    for (int s = 0; s < 8; ++s) c2s[i * 8 + s] = n2[s];
}

// ---------------------------------------------------------------------------
// Shared dense helper: wave w computes rows [16w,16w+16) x all 64 cols of the
// 64x64 tile via 24 MFMAs (hi/lo split), bias added, result -> oT (linear).
// ---------------------------------------------------------------------------
__device__ __forceinline__ void dense_mfma(const float* __restrict__ src,
                                           int arow,  // global row to load
                                           const short8_t* __restrict__ Bh,
                                           const short8_t* __restrict__ Bl,
                                           const float* __restrict__ bias,
                                           float* __restrict__ oT, int w,
                                           int lane) {
    const float* ap = src + (size_t)arow * 64 + ((lane >> 4) << 3);
    f32x4 a0 = *(const f32x4*)(ap);
    f32x4 a1 = *(const f32x4*)(ap + 4);
    f32x4 a2 = *(const f32x4*)(ap + 32);
    f32x4 a3 = *(const f32x4*)(ap + 36);

    short8_t ah0, al0, ah1, al1;
#pragma unroll
    for (int e = 0; e < 4; ++e) {
        unsigned short hh, ll;
        split2(a0[e], hh, ll); ah0[e] = (short)hh; al0[e] = (short)ll;
        split2(a1[e], hh, ll); ah0[4 + e] = (short)hh; al0[4 + e] = (short)ll;
        split2(a2[e], hh, ll); ah1[e] = (short)hh; al1[e] = (short)ll;
        split2(a3[e], hh, ll); ah1[4 + e] = (short)hh; al1[4 + e] = (short)ll;
    }

#pragma unroll 1
    for (int c = 0; c < 4; ++c) {
        short8_t bh0 = Bh[c * 64 + lane];
        short8_t bl0 = Bl[c * 64 + lane];
        short8_t bh1 = Bh[(4 + c) * 64 + lane];
        short8_t bl1 = Bl[(4 + c) * 64 + lane];
        f32x4 acc = {0.f, 0.f, 0.f, 0.f};
        acc = __builtin_amdgcn_mfma_f32_16x16x32_bf16(ah0, bh0, acc, 0, 0, 0);
        acc = __builtin_amdgcn_mfma_f32_16x16x32_bf16(al0, bh0, acc, 0, 0, 0);
        acc = __builtin_amdgcn_mfma_f32_16x16x32_bf16(ah0, bl0, acc, 0, 0, 0);
        acc = __builtin_amdgcn_mfma_f32_16x16x32_bf16(ah1, bh1, acc, 0, 0, 0);
        acc = __builtin_amdgcn_mfma_f32_16x16x32_bf16(al1, bh1, acc, 0, 0, 0);
        acc = __builtin_amdgcn_mfma_f32_16x16x32_bf16(ah1, bl1, acc, 0, 0, 0);
        int col = c * 16 + (lane & 15);
        float bb = bias[col];
#pragma unroll
        for (int r = 0; r < 4; ++r) {
            int row = w * 16 + ((lane >> 4) << 2) + r;
            oT[row * 64 + col] = acc[r] + bb;
        }
    }
}

// fixup: one pair, lane = out channel; fj uniform (scalar), wk coalesced vector
__device__ __forceinline__ void fixup_pair(const float* __restrict__ fj,
                                           const float* __restrict__ wk,
                                           float* __restrict__ oT, int l,
                                           int lane) {
    float a0 = 0.f, a1 = 0.f, a2 = 0.f, a3 = 0.f;
#pragma unroll
    for (int c4 = 0; c4 < 16; ++c4) {
        f32x4 fv = *(const f32x4*)(fj + c4 * 4);
        a0 += fv[0] * wk[(c4 * 4 + 0) * 64 + lane];
        a1 += fv[1] * wk[(c4 * 4 + 1) * 64 + lane];
        a2 += fv[2] * wk[(c4 * 4 + 2) * 64 + lane];
        a3 += fv[3] * wk[(c4 * 4 + 3) * 64 + lane];
    }
    atomicAdd(&oT[l * 64 + lane], (a0 + a1) + (a2 + a3));
}

// ---------------------------------------------------------------------------
__global__ __launch_bounds__(256) void conv1_fused_kernel(
    const float* __restrict__ feats, const float* __restrict__ W1,
    const unsigned short* __restrict__ Wpk1h,
    const unsigned short* __restrict__ Wpk1l, const float* __restrict__ b1,
    const int* __restrict__ c1, const int* __restrict__ p1,
    float* __restrict__ h, int n) {
    __shared__ __align__(16) float oT[4096];
    __shared__ int pl[1 + 64 * 26];
    int base = blockIdx.x * 64;
    int t = threadIdx.x, w = t >> 6, lane = t & 63;

    if (t == 0) pl[0] = 0;
    __syncthreads();
    if (t < 64) {  // compact pairs
        int row = base + t;
        int cnt = (row < n) ? c1[row] : 0;
        if (cnt > 0) {
            int off = atomicAdd(pl, cnt);
            for (int e = 0; e < cnt; ++e)
                pl[1 + off + e] = p1[(size_t)row * CAP1 + e] | (t << 23);
        }
    }

    int arow = base + w * 16 + (lane & 15);
    if (arow >= n) arow = n - 1;
    dense_mfma(feats, arow, (const short8_t*)Wpk1h, (const short8_t*)Wpk1l,
               b1, oT, w, lane);
    __syncthreads();

    int np = pl[0];
    for (int p = w; p < np; p += 4) {
        int se = pl[1 + p];
        se = __builtin_amdgcn_readfirstlane(se);
        int j = se & 0x1FFFF, k = (se >> 17) & 31, l = (se >> 23) & 63;
        fixup_pair(feats + (size_t)j * 64, W1 + (size_t)k * 4096, oT, l, lane);
    }
    __syncthreads();

    {  // SiLU + coalesced store
        int r = t >> 2, q0 = (t & 3) * 16;
        if (base + r < n) {
#pragma unroll
            for (int jj = 0; jj < 4; ++jj) {
                f32x4 v = *(f32x4*)&oT[r * 64 + q0 + jj * 4];
#pragma unroll
                for (int u = 0; u < 4; ++u) v[u] = v[u] / (1.f + __expf(-v[u]));
                *(f32x4*)&h[(size_t)(base + r) * 64 + q0 + jj * 4] = v;
            }
        }
    }
}

// ---------------------------------------------------------------------------
__global__ __launch_bounds__(256) void conv2_fused_kernel(
    const float* __restrict__ h, const unsigned short* __restrict__ Wpk2h,
    const unsigned short* __restrict__ Wpk2l, const float* __restrict__ W2e,
    const float* __restrict__ b2, const int* __restrict__ c2s,
    const int* __restrict__ p2s, float* __restrict__ out, int n) {
    __shared__ __align__(16) float oT[4096];
    __shared__ int pl[1 + 64 * 7];
    int base = blockIdx.x * 64, s = blockIdx.y;
    int t = threadIdx.x, w = t >> 6, lane = t & 63;

    if (t == 0) pl[0] = 0;
    __syncthreads();
    if (t < 64) {
        int row = base + t;
        int cnt = (row < n) ? c2s[(size_t)row * 8 + s] : 0;
        if (cnt > 0) {
            int off = atomicAdd(pl, cnt);
            for (int e = 0; e < cnt; ++e)
                pl[1 + off + e] = p2s[((size_t)row * 8 + s) * CAP2S + e] | (t << 23);
        }
    }

    int arow = base + w * 16 + (lane & 15);
    if (arow >= n) arow = n - 1;
    dense_mfma(h, arow, (const short8_t*)Wpk2h + (size_t)s * 8 * 64,
               (const short8_t*)Wpk2l + (size_t)s * 8 * 64, b2, oT, w, lane);
    __syncthreads();

    int np = pl[0];
    for (int p = w; p < np; p += 4) {
        int se = pl[1 + p];
        se = __builtin_amdgcn_readfirstlane(se);
        int j = se & 0x1FFFF, d = (se >> 17) & 31, l = (se >> 23) & 63;
        fixup_pair(h + (size_t)j * 64, W2e + (size_t)(s * 8 + d) * 4096, oT, l,
                   lane);
    }
    __syncthreads();

    {  // SiLU + store (out row = parent*8 + s)
        int r = t >> 2, q0 = (t & 3) * 16;
        if (base + r < n) {
#pragma unroll
            for (int jj = 0; jj < 4; ++jj) {
                f32x4 v = *(f32x4*)&oT[r * 64 + q0 + jj * 4];
#pragma unroll
                for (int u = 0; u < 4; ++u) v[u] = v[u] / (1.f + __expf(-v[u]));
                *(f32x4*)&out[((size_t)(base + r) * 8 + s) * 64 + q0 + jj * 4] = v;
            }
        }
    }
}

// ---------------------------------------------------------------------------
extern "C" void kernel_launch(void* const* d_in, const int* in_sizes, int n_in,
                              void* d_out, int out_size, void* d_ws,
                              size_t ws_size, hipStream_t stream) {
    const int* coords = (const int*)d_in[0];
    const float* feats = (const float*)d_in[1];
    const float* W1 = (const float*)d_in[2];
    const float* b1 = (const float*)d_in[3];
    const float* W2 = (const float*)d_in[4];
    const float* b2 = (const float*)d_in[5];
    float* out = (float*)d_out;

    int n = in_sizes[0] / 3;  // 20000

    char* ws = (char*)d_ws;
    size_t off = 0;
    auto alloc = [&](size_t bytes) {
        size_t o = off;
        off = (off + bytes + 255) & ~(size_t)255;
        return o;
    };
    unsigned short* grid1 = (unsigned short*)(ws + alloc((size_t)GRID_VOX * 2));
    float* h      = (float*)(ws + alloc((size_t)n * 64 * 4));     // 5.12 MB
    float* W2e    = (float*)(ws + alloc(64 * 4096 * 4));          // 1 MB
    unsigned short* Wpk1h = (unsigned short*)(ws + alloc(512 * 8 * 2));
    unsigned short* Wpk1l = (unsigned short*)(ws + alloc(512 * 8 * 2));
    unsigned short* Wpk2h = (unsigned short*)(ws + alloc(4096 * 8 * 2));
    unsigned short* Wpk2l = (unsigned short*)(ws + alloc(4096 * 8 * 2));
    int*   c1     = (int*)(ws + alloc((size_t)n * 9 * 4));        // c1[n]+c2s[8n]
    int*   c2s    = c1 + n;
    int*   p1     = (int*)(ws + alloc((size_t)n * CAP1 * 4));     // 2.56 MB
    int*   p2s    = (int*)(ws + alloc((size_t)n * 8 * CAP2S * 4)); // 5.12 MB

    // custom fast fill (GRID_VOX*2 bytes = 110592 int4s)
    fill_grid_kernel<<<432, 256, 0, stream>>>((int4*)grid1, GRID_VOX * 2 / 16);

    scatter_grid_kernel<<<(n + 255) / 256, 256, 0, stream>>>(coords, grid1, n);
    prep_weights_kernel<<<(4608 + 64 * 4096 + 255) / 256, 256, 0, stream>>>(
        W1, W2, Wpk1h, Wpk1l, Wpk2h, Wpk2l, W2e);
    build_pairs_kernel<<<(n + 255) / 256, 256, 0, stream>>>(
        coords, grid1, c1, p1, c2s, p2s, n);

    int nblk = (n + 63) / 64;
    conv1_fused_kernel<<<nblk, 256, 0, stream>>>(feats, W1, Wpk1h, Wpk1l, b1,
                                                 c1, p1, h, n);
    conv2_fused_kernel<<<dim3(nblk, 8), 256, 0, stream>>>(
        h, Wpk2h, Wpk2l, W2e, b2, c2s, p2s, out, n);
}